// Round 11
// baseline (228.704 us; speedup 1.0000x reference)
//
#include <hip/hip_runtime.h>
#include <hip/hip_bf16.h>
#include <stdint.h>

#define B_ 2
#define T_ 2048
#define C_ 2048
#define NH_ 16
#define NKVH_ 4
#define HS_ 128
#define QKV_ 3072
#define NTOK_ 4096

typedef __attribute__((ext_vector_type(4))) float f32x4;
typedef __attribute__((ext_vector_type(16))) float f32x16;
typedef __attribute__((ext_vector_type(8))) short s16x8;

__device__ __forceinline__ short f2bf(float f) {
    union { float f; unsigned u; } v; v.f = f;
    unsigned r = v.u + 0x7FFFu + ((v.u >> 16) & 1u);
    return (short)(r >> 16);
}

__device__ __forceinline__ void async16(const void* g, void* l) {
    __builtin_amdgcn_global_load_lds(
        (const __attribute__((address_space(1))) void*)g,
        (__attribute__((address_space(3))) void*)l, 16, 0, 0);
}

// ---------------- cast x -> bf16 ----------------
__global__ void cast_bf16_kernel(const float* __restrict__ x, short* __restrict__ out, int n8) {
    int i = blockIdx.x * 256 + threadIdx.x;
    if (i >= n8) return;
    const float4* p = (const float4*)x + (size_t)i * 2;
    float4 a = p[0], b = p[1];
    short o[8] = { f2bf(a.x), f2bf(a.y), f2bf(a.z), f2bf(a.w),
                   f2bf(b.x), f2bf(b.y), f2bf(b.z), f2bf(b.w) };
    *(int4*)(out + (size_t)i * 8) = *(const int4*)o;
}

// ---------------- W [K][N] f32 -> WT [N][K] bf16 ----------------
__global__ void transcast(const float* __restrict__ W, short* __restrict__ WT, int Kd, int Nd) {
    __shared__ float tile[64][65];
    int k0 = blockIdx.x * 64, n0 = blockIdx.y * 64;
    int tid = threadIdx.x;
    int cl = tid & 63, rw = tid >> 6;
    for (int it = 0; it < 16; ++it) {
        int r = it * 4 + rw;
        tile[r][cl] = W[(size_t)(k0 + r) * Nd + n0 + cl];
    }
    __syncthreads();
    for (int it = 0; it < 16; ++it) {
        int n = it * 4 + rw;
        WT[(size_t)(n0 + n) * Kd + k0 + cl] = f2bf(tile[cl][n]);
    }
}

// ---------------- GEMM: A[M][K] bf16 x Bt[N][K] bf16 -> C[M][N] f32 + bias ----------------
__global__ __launch_bounds__(256, 2) void gemm_bt(
    const short* __restrict__ A, const short* __restrict__ Bt,
    const float* __restrict__ bias, float* __restrict__ Cc,
    int M, int N, int K)
{
    __shared__ short As[128 * 64];
    __shared__ short Bs[128 * 64];
    int tid = threadIdx.x;
    int w = tid >> 6, l = tid & 63;
    int lr = l & 15, lg = l >> 4;
    int bm = blockIdx.x, bn = blockIdx.y;
    int wm = (w >> 1) * 64, wn = (w & 1) * 64;
    f32x4 acc[4][4];
#pragma unroll
    for (int i = 0; i < 4; i++)
#pragma unroll
        for (int j = 0; j < 4; j++) { acc[i][j][0]=0.f; acc[i][j][1]=0.f; acc[i][j][2]=0.f; acc[i][j][3]=0.f; }
    int arow = l >> 3, acol = (l & 7) * 8;
    for (int k0 = 0; k0 < K; k0 += 64) {
#pragma unroll
        for (int i = 0; i < 4; i++) {
            int chunk = w * 4 + i;
            int row = chunk * 8 + arow;
            async16(A  + (size_t)(bm * 128 + row) * K + k0 + acol, (char*)As + chunk * 1024);
            async16(Bt + (size_t)(bn * 128 + row) * K + k0 + acol, (char*)Bs + chunk * 1024);
        }
        __syncthreads();
#pragma unroll
        for (int ks = 0; ks < 2; ks++) {
            s16x8 af[4], bf[4];
#pragma unroll
            for (int mi = 0; mi < 4; mi++)
                af[mi] = *(const s16x8*)&As[(wm + mi * 16 + lr) * 64 + ks * 32 + lg * 8];
#pragma unroll
            for (int ni = 0; ni < 4; ni++)
                bf[ni] = *(const s16x8*)&Bs[(wn + ni * 16 + lr) * 64 + ks * 32 + lg * 8];
#pragma unroll
            for (int mi = 0; mi < 4; mi++)
#pragma unroll
                for (int ni = 0; ni < 4; ni++)
                    acc[mi][ni] = __builtin_amdgcn_mfma_f32_16x16x32_bf16(af[mi], bf[ni], acc[mi][ni], 0, 0, 0);
        }
        __syncthreads();
    }
#pragma unroll
    for (int mi = 0; mi < 4; mi++) {
        int row = bm * 128 + wm + mi * 16 + lg * 4;
#pragma unroll
        for (int ni = 0; ni < 4; ni++) {
            int col = bn * 128 + wn + ni * 16 + lr;
            float bv = bias[col];
#pragma unroll
            for (int j = 0; j < 4; j++)
                Cc[(size_t)(row + j) * N + col] = acc[mi][ni][j] + bv;
        }
    }
}

// ---------------- RoPE + scatter to Q [B][NH][T][HS] (pre-scaled by 1/sqrt(HS)), K [B][G][T][HS] bf16 ----------------
__global__ void rope_scatter(const float* __restrict__ qkv,
                             const float* __restrict__ fcos, const float* __restrict__ fsin,
                             short* __restrict__ Q, short* __restrict__ Kb)
{
    const float qscale = 0.08838834764831845f; // 1/sqrt(128), folded into Q
    int idx = blockIdx.x * 256 + threadIdx.x;
    int tok = idx / 1280, p = idx - tok * 1280;
    if (tok >= NTOK_) return;
    int b = tok >> 11, t = tok & 2047;
    if (p < 1024) {
        int h = p >> 6, i = p & 63;
        const float* src = qkv + (size_t)tok * QKV_ + h * 128 + 2 * i;
        float re = src[0], im = src[1];
        float c = fcos[t * 64 + i], s = fsin[t * 64 + i];
        unsigned lo = (unsigned short)f2bf((re * c - im * s) * qscale);
        unsigned hi = (unsigned short)f2bf((re * s + im * c) * qscale);
        *(unsigned*)(Q + ((size_t)(b * NH_ + h) * T_ + t) * HS_ + 2 * i) = lo | (hi << 16);
    } else {
        int pk = p - 1024; int g = pk >> 6, i = pk & 63;
        const float* src = qkv + (size_t)tok * QKV_ + C_ + g * 128 + 2 * i;
        float re = src[0], im = src[1];
        float c = fcos[t * 64 + i], s = fsin[t * 64 + i];
        unsigned lo = (unsigned short)f2bf(re * c - im * s);
        unsigned hi = (unsigned short)f2bf(re * s + im * c);
        *(unsigned*)(Kb + ((size_t)(b * NKVH_ + g) * T_ + t) * HS_ + 2 * i) = lo | (hi << 16);
    }
}

// ---------------- V part of qkv -> VT [B][G][HS][T] bf16 ----------------
__global__ void v_transpose(const float* __restrict__ qkv, short* __restrict__ VT) {
    __shared__ float tile[64][65];
    int t0 = blockIdx.x * 64, d0 = blockIdx.y * 64;
    int bg = blockIdx.z; int b = bg >> 2, g = bg & 3;
    int tid = threadIdx.x; int cl = tid & 63, rw = tid >> 6;
    const float* base = qkv + (size_t)(b * T_ + t0) * QKV_ + C_ + NKVH_ * HS_ + g * HS_ + d0;
    for (int it = 0; it < 16; ++it) {
        int r = it * 4 + rw;
        tile[r][cl] = base[(size_t)r * QKV_ + cl];
    }
    __syncthreads();
    short* out = VT + ((size_t)(b * NKVH_ + g) * HS_ + d0) * T_ + t0;
    for (int it = 0; it < 16; ++it) {
        int d = it * 4 + rw;
        out[(size_t)d * T_ + cl] = f2bf(tile[cl][d]);
    }
}

// ---------------- Flash attention, causal GQA — swapped-QK^T 32x32, PAIRED q-tiles ----------------
// grid: (B*NH=32, 8 pairs). block: 256 (4 waves x 32 q-rows). Each block processes q-tile
// p AND q-tile 15-p sequentially -> EVERY block = exactly 34 tile-units (perfect balance).
// ROUND-10 LESSON: with 512 unequal blocks (1..32 units) the dispatch can pair two 32-unit
// blocks on one CU -> ~64-unit serial tail; occupancy 12.8% matched the slot-busy=53% model.
// 256 equal blocks = 1/CU, no pairing lottery; duration = 34 uncontended units.
// S^T = mfma32x32x16(A=K_lds, B=Q_reg); P via wave-private swizzled LDS (packed b64 writes);
// O^T = mfma32x32x16(A=V_lds, B=P). 2-phase dbuf K+V prefetch, 1 barrier/tile. T5 setprio.
// launch_bounds(256,2): (256,4) spills (round 2). grid.x MUST be 32 (b=bh>>4, round 3).
__global__ __launch_bounds__(256, 2) void attn_kernel(
    const short* __restrict__ Qg, const short* __restrict__ Kg,
    const short* __restrict__ VTg, short* __restrict__ Y)
{
    __shared__ short Ks[2][64 * 128];   // [buf][s][d], swizzled (256B rows, XOR (row&7)<<4)
    __shared__ short VTs[2][128 * 64];  // [buf][d][s], swizzled (128B rows, XOR (row&7)<<4)
    __shared__ short Ps[4][32 * 64];    // per-wave P: [q 32][s 64], swizzled 128B rows
    int tid = threadIdx.x, w = tid >> 6, l = tid & 63;
    int l31 = l & 31, hi = l >> 5;
    int pid = blockIdx.y;            // pair index 0..7
    int bh = blockIdx.x;
    int b = bh >> 4, h = bh & 15, g = h >> 2;
    const short* Qb = Qg + (size_t)(b * NH_ + h) * T_ * HS_;
    const short* Kb = Kg + (size_t)(b * NKVH_ + g) * T_ * HS_;
    const short* Vb = VTg + (size_t)(b * NKVH_ + g) * HS_ * T_;

    auto STAGE = [&](int st, int buf) {
#pragma unroll
        for (int i = 0; i < 4; i++) {
            int chunk = w * 4 + i;
            int poff = chunk * 1024 + l * 16;
            int qoffk = poff ^ (((poff >> 8) & 7) << 4);
            async16(Kb + (size_t)(st * 64 + (qoffk >> 8)) * HS_ + ((qoffk & 255) >> 1),
                    (char*)&Ks[buf][0] + chunk * 1024);
            int qoffv = poff ^ (((poff >> 7) & 7) << 4);
            async16(Vb + (size_t)(qoffv >> 7) * T_ + st * 64 + ((qoffv & 127) >> 1),
                    (char*)&VTs[buf][0] + chunk * 1024);
        }
    };

    for (int pass = 0; pass < 2; ++pass) {
        int qt = pass ? (15 - pid) : pid;
        int qw = qt * 128 + w * 32;      // wave's first q-row
        int qglob = qw + l31;            // this lane's q-row

        // Q fragment (B-operand): lane holds Q[qglob][d = dc*16 + hi*8 + i]
        s16x8 qf[8];
#pragma unroll
        for (int dc = 0; dc < 8; dc++)
            qf[dc] = *(const s16x8*)(Qb + (size_t)qglob * HS_ + dc * 16 + hi * 8);

        // O^T accumulators: oacc[db][r] = O[d = db*32 + (r&3)+8*(r>>2)+4*hi][qglob]
        f32x16 oacc[4];
#pragma unroll
        for (int db = 0; db < 4; db++)
#pragma unroll
            for (int i = 0; i < 16; i++) oacc[db][i] = 0.f;
        float m = -1e30f, lsum = 0.f;
        int nst = 2 * qt + 2;

        STAGE(0, 0);
        __syncthreads();
        int cur = 0;

        for (int st = 0; st < nst; ++st) {
            if (st + 1 < nst) STAGE(st + 1, cur ^ 1);   // K+V prefetch flies under compute
            if (st * 64 <= qw) {                        // skip fully-masked tiles (wave-uniform)
                const char* KsC = (const char*)&Ks[cur][0];
                const char* VsC = (const char*)&VTs[cur][0];
                char* PsC = (char*)&Ps[w][0];

                // S^T[s][q] = sum_d K[s][d] * Q[q][d]  (Q pre-scaled); 2 acc chains per s-block
                f32x16 sacc[2];
                __builtin_amdgcn_s_setprio(1);
#pragma unroll
                for (int sb = 0; sb < 2; sb++) {
                    f32x16 a0, a1;
#pragma unroll
                    for (int i = 0; i < 16; i++) { a0[i] = 0.f; a1[i] = 0.f; }
#pragma unroll
                    for (int dc = 0; dc < 4; dc++) {
                        int lo0 = (sb * 32 + l31) * 256 + dc * 32 + hi * 16;
                        int po0 = lo0 ^ (((lo0 >> 8) & 7) << 4);
                        s16x8 kf0 = *(const s16x8*)(KsC + po0);
                        a0 = __builtin_amdgcn_mfma_f32_32x32x16_bf16(kf0, qf[dc], a0, 0, 0, 0);
                        int lo1 = (sb * 32 + l31) * 256 + (dc + 4) * 32 + hi * 16;
                        int po1 = lo1 ^ (((lo1 >> 8) & 7) << 4);
                        s16x8 kf1 = *(const s16x8*)(KsC + po1);
                        a1 = __builtin_amdgcn_mfma_f32_32x32x16_bf16(kf1, qf[dc + 4], a1, 0, 0, 0);
                    }
#pragma unroll
                    for (int i = 0; i < 16; i++) a0[i] += a1[i];
                    sacc[sb] = a0;
                }
                __builtin_amdgcn_s_setprio(0);
                // causal mask (boundary tiles only); lane's s-rows: sb*32 + (r&3)+8*(r>>2)+4*hi
                if (st * 64 + 63 > qw) {
#pragma unroll
                    for (int sb = 0; sb < 2; sb++)
#pragma unroll
                        for (int r = 0; r < 16; r++) {
                            int s = st * 64 + sb * 32 + (r & 3) + 8 * (r >> 2) + 4 * hi;
                            if (s > qglob) sacc[sb][r] = -1e30f;
                        }
                }
                // row max: local fmax + 1 cross-half merge
                float tm = -1e30f;
#pragma unroll
                for (int sb = 0; sb < 2; sb++)
#pragma unroll
                    for (int r = 0; r < 16; r++) tm = fmaxf(tm, sacc[sb][r]);
                tm = fmaxf(tm, __shfl_xor(tm, 32));
                // exact defer-rescale
                if (__any(tm > m)) {
                    float mn = fmaxf(m, tm);
                    float corr = __expf(m - mn);
                    m = mn; lsum *= corr;
#pragma unroll
                    for (int db = 0; db < 4; db++)
#pragma unroll
                        for (int r = 0; r < 16; r++) oacc[db][r] *= corr;
                }
                // P = exp(S^T - m) -> LDS row q=l31, XOR-swizzled; 4 bf16 per ds_write_b64
#pragma unroll
                for (int sb = 0; sb < 2; sb++)
#pragma unroll
                    for (int k = 0; k < 4; k++) {
                        float p0 = __expf(sacc[sb][4 * k]     - m);
                        float p1 = __expf(sacc[sb][4 * k + 1] - m);
                        float p2 = __expf(sacc[sb][4 * k + 2] - m);
                        float p3 = __expf(sacc[sb][4 * k + 3] - m);
                        lsum += (p0 + p1) + (p2 + p3);
                        unsigned w01 = (unsigned short)f2bf(p0) | ((unsigned)(unsigned short)f2bf(p1) << 16);
                        unsigned w23 = (unsigned short)f2bf(p2) | ((unsigned)(unsigned short)f2bf(p3) << 16);
                        uint2 pkv; pkv.x = w01; pkv.y = w23;
                        int sl = sb * 32 + 8 * k + 4 * hi;
                        int lo = l31 * 128 + sl * 2;
                        int po = lo ^ (((lo >> 7) & 7) << 4);
                        *(uint2*)(PsC + po) = pkv;
                    }
                // O^T += V^T · P  (A = V^T d-rows from LDS, B = P from LDS)
                __builtin_amdgcn_s_setprio(1);
#pragma unroll
                for (int sc = 0; sc < 4; sc++) {
                    unsigned ptmp[4];
                    int lp = l31 * 128 + sc * 32 + hi * 16;
                    int pp = lp ^ (((lp >> 7) & 7) << 4);
                    *(uint2*)&ptmp[0] = *(const uint2*)(PsC + pp);
                    *(uint2*)&ptmp[2] = *(const uint2*)(PsC + pp + 8);
                    s16x8 pf = *(const s16x8*)ptmp;
#pragma unroll
                    for (int db = 0; db < 4; db++) {
                        int lo = (db * 32 + l31) * 128 + sc * 32 + hi * 16;
                        int po = lo ^ (((lo >> 7) & 7) << 4);
                        s16x8 vf = *(const s16x8*)(VsC + po);
                        oacc[db] = __builtin_amdgcn_mfma_f32_32x32x16_bf16(vf, pf, oacc[db], 0, 0, 0);
                    }
                }
                __builtin_amdgcn_s_setprio(0);
            }
            __syncthreads();   // implicit vmcnt(0): prefetch landed; buf[cur] free
            cur ^= 1;
        }

        // epilogue: merge half-row sums, normalize, write O (pairs of consecutive d)
        lsum += __shfl_xor(lsum, 32);
        float inv = 1.0f / lsum;
        short* Yrow = Y + (size_t)(b * T_ + qglob) * C_ + h * 128;
#pragma unroll
        for (int db = 0; db < 4; db++)
#pragma unroll
            for (int pr = 0; pr < 8; pr++) {
                unsigned u0 = (unsigned short)f2bf(oacc[db][2 * pr] * inv);
                unsigned u1 = (unsigned short)f2bf(oacc[db][2 * pr + 1] * inv);
                int d = db * 32 + ((2 * pr) & 3) + 8 * (pr >> 1) + 4 * hi;
                *(unsigned*)(Yrow + d) = u0 | (u1 << 16);
            }
        // pass A's final __syncthreads already fenced LDS reuse for pass B's STAGE(0,0)
    }
}

extern "C" void kernel_launch(void* const* d_in, const int* in_sizes, int n_in,
                              void* d_out, int out_size, void* d_ws, size_t ws_size,
                              hipStream_t stream)
{
    const float* x      = (const float*)d_in[0];
    const float* fcos   = (const float*)d_in[1];
    const float* fsin   = (const float*)d_in[2];
    const float* W_attn = (const float*)d_in[3];
    const float* b_attn = (const float*)d_in[4];
    const float* W_proj = (const float*)d_in[5];
    const float* b_proj = (const float*)d_in[6];
    float* out = (float*)d_out;
    char* ws = (char*)d_ws;

    // workspace layout (92.3 MB, with dead-buffer aliasing)
    short* xb  = (short*)(ws + 0);          // 16,777,216
    float* qkv = (float*)(ws + 16777216);   // 50,331,648  [16777216 .. 67108864)
    short* y   = (short*)(ws + 16777216);   // alias qkv lower (qkv dead by then)
    short* WpT = (short*)(ws + 33554432);   // alias qkv upper, 8,388,608
    short* WaT = (short*)(ws + 67108864);   // 12,582,912
    short* Qb  = (short*)(ws + 67108864);   // alias WaT (dead after gemm1), 16,777,216
    short* Kb  = (short*)(ws + 83886080);   // 4,194,304
    short* VT  = (short*)(ws + 88080384);   // 4,194,304

    cast_bf16_kernel<<<4096, 256, 0, stream>>>(x, xb, NTOK_ * C_ / 8);
    transcast<<<dim3(32, 48), 256, 0, stream>>>(W_attn, WaT, C_, QKV_);
    gemm_bt<<<dim3(32, 24), 256, 0, stream>>>(xb, WaT, b_attn, qkv, NTOK_, QKV_, C_);
    rope_scatter<<<20480, 256, 0, stream>>>(qkv, fcos, fsin, Qb, Kb);
    v_transpose<<<dim3(32, 2, 8), 256, 0, stream>>>(qkv, VT);
    transcast<<<dim3(32, 32), 256, 0, stream>>>(W_proj, WpT, C_, C_);
    attn_kernel<<<dim3(32, 8), 256, 0, stream>>>(Qb, Kb, VT, y);
    gemm_bt<<<dim3(32, 16), 256, 0, stream>>>(y, WpT, b_proj, out, NTOK_, C_, C_);
}

// Round 12
// 223.933 us; speedup vs baseline: 1.0213x; 1.0213x over previous
//
#include <hip/hip_runtime.h>
#include <hip/hip_bf16.h>
#include <stdint.h>

#define B_ 2
#define T_ 2048
#define C_ 2048
#define NH_ 16
#define NKVH_ 4
#define HS_ 128
#define QKV_ 3072
#define NTOK_ 4096

typedef __attribute__((ext_vector_type(4))) float f32x4;
typedef __attribute__((ext_vector_type(16))) float f32x16;
typedef __attribute__((ext_vector_type(8))) short s16x8;

__device__ __forceinline__ short f2bf(float f) {
    union { float f; unsigned u; } v; v.f = f;
    unsigned r = v.u + 0x7FFFu + ((v.u >> 16) & 1u);
    return (short)(r >> 16);
}

__device__ __forceinline__ void async16(const void* g, void* l) {
    __builtin_amdgcn_global_load_lds(
        (const __attribute__((address_space(1))) void*)g,
        (__attribute__((address_space(3))) void*)l, 16, 0, 0);
}

// ---------------- cast x -> bf16 ----------------
__global__ void cast_bf16_kernel(const float* __restrict__ x, short* __restrict__ out, int n8) {
    int i = blockIdx.x * 256 + threadIdx.x;
    if (i >= n8) return;
    const float4* p = (const float4*)x + (size_t)i * 2;
    float4 a = p[0], b = p[1];
    short o[8] = { f2bf(a.x), f2bf(a.y), f2bf(a.z), f2bf(a.w),
                   f2bf(b.x), f2bf(b.y), f2bf(b.z), f2bf(b.w) };
    *(int4*)(out + (size_t)i * 8) = *(const int4*)o;
}

// ---------------- W [K][N] f32 -> WT [N][K] bf16 ----------------
__global__ void transcast(const float* __restrict__ W, short* __restrict__ WT, int Kd, int Nd) {
    __shared__ float tile[64][65];
    int k0 = blockIdx.x * 64, n0 = blockIdx.y * 64;
    int tid = threadIdx.x;
    int cl = tid & 63, rw = tid >> 6;
    for (int it = 0; it < 16; ++it) {
        int r = it * 4 + rw;
        tile[r][cl] = W[(size_t)(k0 + r) * Nd + n0 + cl];
    }
    __syncthreads();
    for (int it = 0; it < 16; ++it) {
        int n = it * 4 + rw;
        WT[(size_t)(n0 + n) * Kd + k0 + cl] = f2bf(tile[cl][n]);
    }
}

// ---------------- GEMM: A[M][K] bf16 x Bt[N][K] bf16 -> C[M][N] f32 + bias ----------------
__global__ __launch_bounds__(256, 2) void gemm_bt(
    const short* __restrict__ A, const short* __restrict__ Bt,
    const float* __restrict__ bias, float* __restrict__ Cc,
    int M, int N, int K)
{
    __shared__ short As[128 * 64];
    __shared__ short Bs[128 * 64];
    int tid = threadIdx.x;
    int w = tid >> 6, l = tid & 63;
    int lr = l & 15, lg = l >> 4;
    int bm = blockIdx.x, bn = blockIdx.y;
    int wm = (w >> 1) * 64, wn = (w & 1) * 64;
    f32x4 acc[4][4];
#pragma unroll
    for (int i = 0; i < 4; i++)
#pragma unroll
        for (int j = 0; j < 4; j++) { acc[i][j][0]=0.f; acc[i][j][1]=0.f; acc[i][j][2]=0.f; acc[i][j][3]=0.f; }
    int arow = l >> 3, acol = (l & 7) * 8;
    for (int k0 = 0; k0 < K; k0 += 64) {
#pragma unroll
        for (int i = 0; i < 4; i++) {
            int chunk = w * 4 + i;
            int row = chunk * 8 + arow;
            async16(A  + (size_t)(bm * 128 + row) * K + k0 + acol, (char*)As + chunk * 1024);
            async16(Bt + (size_t)(bn * 128 + row) * K + k0 + acol, (char*)Bs + chunk * 1024);
        }
        __syncthreads();
#pragma unroll
        for (int ks = 0; ks < 2; ks++) {
            s16x8 af[4], bf[4];
#pragma unroll
            for (int mi = 0; mi < 4; mi++)
                af[mi] = *(const s16x8*)&As[(wm + mi * 16 + lr) * 64 + ks * 32 + lg * 8];
#pragma unroll
            for (int ni = 0; ni < 4; ni++)
                bf[ni] = *(const s16x8*)&Bs[(wn + ni * 16 + lr) * 64 + ks * 32 + lg * 8];
#pragma unroll
            for (int mi = 0; mi < 4; mi++)
#pragma unroll
                for (int ni = 0; ni < 4; ni++)
                    acc[mi][ni] = __builtin_amdgcn_mfma_f32_16x16x32_bf16(af[mi], bf[ni], acc[mi][ni], 0, 0, 0);
        }
        __syncthreads();
    }
#pragma unroll
    for (int mi = 0; mi < 4; mi++) {
        int row = bm * 128 + wm + mi * 16 + lg * 4;
#pragma unroll
        for (int ni = 0; ni < 4; ni++) {
            int col = bn * 128 + wn + ni * 16 + lr;
            float bv = bias[col];
#pragma unroll
            for (int j = 0; j < 4; j++)
                Cc[(size_t)(row + j) * N + col] = acc[mi][ni][j] + bv;
        }
    }
}

// ---------------- RoPE + scatter to Q [B][NH][T][HS] (pre-scaled by 1/sqrt(HS)), K [B][G][T][HS] bf16 ----------------
__global__ void rope_scatter(const float* __restrict__ qkv,
                             const float* __restrict__ fcos, const float* __restrict__ fsin,
                             short* __restrict__ Q, short* __restrict__ Kb)
{
    const float qscale = 0.08838834764831845f; // 1/sqrt(128), folded into Q
    int idx = blockIdx.x * 256 + threadIdx.x;
    int tok = idx / 1280, p = idx - tok * 1280;
    if (tok >= NTOK_) return;
    int b = tok >> 11, t = tok & 2047;
    if (p < 1024) {
        int h = p >> 6, i = p & 63;
        const float* src = qkv + (size_t)tok * QKV_ + h * 128 + 2 * i;
        float re = src[0], im = src[1];
        float c = fcos[t * 64 + i], s = fsin[t * 64 + i];
        unsigned lo = (unsigned short)f2bf((re * c - im * s) * qscale);
        unsigned hi = (unsigned short)f2bf((re * s + im * c) * qscale);
        *(unsigned*)(Q + ((size_t)(b * NH_ + h) * T_ + t) * HS_ + 2 * i) = lo | (hi << 16);
    } else {
        int pk = p - 1024; int g = pk >> 6, i = pk & 63;
        const float* src = qkv + (size_t)tok * QKV_ + C_ + g * 128 + 2 * i;
        float re = src[0], im = src[1];
        float c = fcos[t * 64 + i], s = fsin[t * 64 + i];
        unsigned lo = (unsigned short)f2bf(re * c - im * s);
        unsigned hi = (unsigned short)f2bf(re * s + im * c);
        *(unsigned*)(Kb + ((size_t)(b * NKVH_ + g) * T_ + t) * HS_ + 2 * i) = lo | (hi << 16);
    }
}

// ---------------- V part of qkv -> VT [B][G][HS][T] bf16 ----------------
__global__ void v_transpose(const float* __restrict__ qkv, short* __restrict__ VT) {
    __shared__ float tile[64][65];
    int t0 = blockIdx.x * 64, d0 = blockIdx.y * 64;
    int bg = blockIdx.z; int b = bg >> 2, g = bg & 3;
    int tid = threadIdx.x; int cl = tid & 63, rw = tid >> 6;
    const float* base = qkv + (size_t)(b * T_ + t0) * QKV_ + C_ + NKVH_ * HS_ + g * HS_ + d0;
    for (int it = 0; it < 16; ++it) {
        int r = it * 4 + rw;
        tile[r][cl] = base[(size_t)r * QKV_ + cl];
    }
    __syncthreads();
    short* out = VT + ((size_t)(b * NKVH_ + g) * HS_ + d0) * T_ + t0;
    for (int it = 0; it < 16; ++it) {
        int d = it * 4 + rw;
        out[(size_t)d * T_ + cl] = f2bf(tile[cl][d]);
    }
}

// ---------------- Flash attention, causal GQA — swapped-QK^T 32x32, CU-paired grid ----------------
// grid: (B*NH=32 fast, 16 y). block: 256 (4 waves x 32 q-rows), ONE 128-row q-tile per block.
// ALL 512 blocks co-resident (80KB x2 = 160KB LDS, 2 blocks/CU). ROUND-11 LESSON: 1 block/CU
// (perfectly balanced pairs inside one block) was SLOWER (88 vs 82us) — co-residency is the
// latency hider. ROUND-10 LESSON: with qt=15-y mapping, CU c hosts blocks i=c & i+256 whose
// qt differ by 8 -> per-CU load 20..48 units (occupancy 12.8% matched this model).
// FIX: complementary mapping qt = (y<8) ? y : 23-y -> blocks i and i+256 have qt summing
// to 15 -> EVERY CU gets exactly 34 units, with 2-block overlap. Perf-only heuristic.
// S^T = mfma32x32x16(A=K_lds, B=Q_reg); P via wave-private swizzled LDS (packed b64);
// O^T = mfma32x32x16(A=V_lds, B=P). 2-phase dbuf K+V prefetch, 1 barrier/tile. T5 setprio.
// launch_bounds(256,2): (256,4) spills (round 2). grid.x MUST be 32 (b=bh>>4, round 3).
__global__ __launch_bounds__(256, 2) void attn_kernel(
    const short* __restrict__ Qg, const short* __restrict__ Kg,
    const short* __restrict__ VTg, short* __restrict__ Y)
{
    __shared__ short Ks[2][64 * 128];   // [buf][s][d], swizzled (256B rows, XOR (row&7)<<4)
    __shared__ short VTs[2][128 * 64];  // [buf][d][s], swizzled (128B rows, XOR (row&7)<<4)
    __shared__ short Ps[4][32 * 64];    // per-wave P: [q 32][s 64], swizzled 128B rows
    int tid = threadIdx.x, w = tid >> 6, l = tid & 63;
    int l31 = l & 31, hi = l >> 5;
    int yy = blockIdx.y;
    int qt = (yy < 8) ? yy : 23 - yy;   // CU-complementary pairing (see header comment)
    int bh = blockIdx.x;
    int b = bh >> 4, h = bh & 15, g = h >> 2;
    const short* Qb = Qg + (size_t)(b * NH_ + h) * T_ * HS_;
    const short* Kb = Kg + (size_t)(b * NKVH_ + g) * T_ * HS_;
    const short* Vb = VTg + (size_t)(b * NKVH_ + g) * HS_ * T_;

    auto STAGE = [&](int st, int buf) {
#pragma unroll
        for (int i = 0; i < 4; i++) {
            int chunk = w * 4 + i;
            int poff = chunk * 1024 + l * 16;
            int qoffk = poff ^ (((poff >> 8) & 7) << 4);
            async16(Kb + (size_t)(st * 64 + (qoffk >> 8)) * HS_ + ((qoffk & 255) >> 1),
                    (char*)&Ks[buf][0] + chunk * 1024);
            int qoffv = poff ^ (((poff >> 7) & 7) << 4);
            async16(Vb + (size_t)(qoffv >> 7) * T_ + st * 64 + ((qoffv & 127) >> 1),
                    (char*)&VTs[buf][0] + chunk * 1024);
        }
    };

    int qw = qt * 128 + w * 32;      // wave's first q-row
    int qglob = qw + l31;            // this lane's q-row

    // Q fragment (B-operand): lane holds Q[qglob][d = dc*16 + hi*8 + i]
    s16x8 qf[8];
#pragma unroll
    for (int dc = 0; dc < 8; dc++)
        qf[dc] = *(const s16x8*)(Qb + (size_t)qglob * HS_ + dc * 16 + hi * 8);

    // O^T accumulators: oacc[db][r] = O[d = db*32 + (r&3)+8*(r>>2)+4*hi][qglob]
    f32x16 oacc[4];
#pragma unroll
    for (int db = 0; db < 4; db++)
#pragma unroll
        for (int i = 0; i < 16; i++) oacc[db][i] = 0.f;
    float m = -1e30f, lsum = 0.f;
    int nst = 2 * qt + 2;

    STAGE(0, 0);
    __syncthreads();
    int cur = 0;

    for (int st = 0; st < nst; ++st) {
        if (st + 1 < nst) STAGE(st + 1, cur ^ 1);   // K+V prefetch flies under compute
        if (st * 64 <= qw) {                        // skip fully-masked tiles (wave-uniform)
            const char* KsC = (const char*)&Ks[cur][0];
            const char* VsC = (const char*)&VTs[cur][0];
            char* PsC = (char*)&Ps[w][0];

            // S^T[s][q] = sum_d K[s][d] * Q[q][d]  (Q pre-scaled); 2 acc chains per s-block
            f32x16 sacc[2];
            __builtin_amdgcn_s_setprio(1);
#pragma unroll
            for (int sb = 0; sb < 2; sb++) {
                f32x16 a0, a1;
#pragma unroll
                for (int i = 0; i < 16; i++) { a0[i] = 0.f; a1[i] = 0.f; }
#pragma unroll
                for (int dc = 0; dc < 4; dc++) {
                    int lo0 = (sb * 32 + l31) * 256 + dc * 32 + hi * 16;
                    int po0 = lo0 ^ (((lo0 >> 8) & 7) << 4);
                    s16x8 kf0 = *(const s16x8*)(KsC + po0);
                    a0 = __builtin_amdgcn_mfma_f32_32x32x16_bf16(kf0, qf[dc], a0, 0, 0, 0);
                    int lo1 = (sb * 32 + l31) * 256 + (dc + 4) * 32 + hi * 16;
                    int po1 = lo1 ^ (((lo1 >> 8) & 7) << 4);
                    s16x8 kf1 = *(const s16x8*)(KsC + po1);
                    a1 = __builtin_amdgcn_mfma_f32_32x32x16_bf16(kf1, qf[dc + 4], a1, 0, 0, 0);
                }
#pragma unroll
                for (int i = 0; i < 16; i++) a0[i] += a1[i];
                sacc[sb] = a0;
            }
            __builtin_amdgcn_s_setprio(0);
            // causal mask (boundary tiles only); lane's s-rows: sb*32 + (r&3)+8*(r>>2)+4*hi
            if (st * 64 + 63 > qw) {
#pragma unroll
                for (int sb = 0; sb < 2; sb++)
#pragma unroll
                    for (int r = 0; r < 16; r++) {
                        int s = st * 64 + sb * 32 + (r & 3) + 8 * (r >> 2) + 4 * hi;
                        if (s > qglob) sacc[sb][r] = -1e30f;
                    }
            }
            // row max: local fmax + 1 cross-half merge
            float tm = -1e30f;
#pragma unroll
            for (int sb = 0; sb < 2; sb++)
#pragma unroll
                for (int r = 0; r < 16; r++) tm = fmaxf(tm, sacc[sb][r]);
            tm = fmaxf(tm, __shfl_xor(tm, 32));
            // exact defer-rescale
            if (__any(tm > m)) {
                float mn = fmaxf(m, tm);
                float corr = __expf(m - mn);
                m = mn; lsum *= corr;
#pragma unroll
                for (int db = 0; db < 4; db++)
#pragma unroll
                    for (int r = 0; r < 16; r++) oacc[db][r] *= corr;
            }
            // P = exp(S^T - m) -> LDS row q=l31, XOR-swizzled; 4 bf16 per ds_write_b64
            // (r = 4k..4k+3 have consecutive s = sb*32 + 8k + 4hi + 0..3)
#pragma unroll
            for (int sb = 0; sb < 2; sb++)
#pragma unroll
                for (int k = 0; k < 4; k++) {
                    float p0 = __expf(sacc[sb][4 * k]     - m);
                    float p1 = __expf(sacc[sb][4 * k + 1] - m);
                    float p2 = __expf(sacc[sb][4 * k + 2] - m);
                    float p3 = __expf(sacc[sb][4 * k + 3] - m);
                    lsum += (p0 + p1) + (p2 + p3);
                    unsigned w01 = (unsigned short)f2bf(p0) | ((unsigned)(unsigned short)f2bf(p1) << 16);
                    unsigned w23 = (unsigned short)f2bf(p2) | ((unsigned)(unsigned short)f2bf(p3) << 16);
                    uint2 pkv; pkv.x = w01; pkv.y = w23;
                    int sl = sb * 32 + 8 * k + 4 * hi;
                    int lo = l31 * 128 + sl * 2;
                    int po = lo ^ (((lo >> 7) & 7) << 4);
                    *(uint2*)(PsC + po) = pkv;
                }
            // O^T += V^T · P  (A = V^T d-rows from LDS, B = P from LDS)
            __builtin_amdgcn_s_setprio(1);
#pragma unroll
            for (int sc = 0; sc < 4; sc++) {
                unsigned ptmp[4];
                int lp = l31 * 128 + sc * 32 + hi * 16;
                int pp = lp ^ (((lp >> 7) & 7) << 4);
                *(uint2*)&ptmp[0] = *(const uint2*)(PsC + pp);
                *(uint2*)&ptmp[2] = *(const uint2*)(PsC + pp + 8);
                s16x8 pf = *(const s16x8*)ptmp;
#pragma unroll
                for (int db = 0; db < 4; db++) {
                    int lo = (db * 32 + l31) * 128 + sc * 32 + hi * 16;
                    int po = lo ^ (((lo >> 7) & 7) << 4);
                    s16x8 vf = *(const s16x8*)(VsC + po);
                    oacc[db] = __builtin_amdgcn_mfma_f32_32x32x16_bf16(vf, pf, oacc[db], 0, 0, 0);
                }
            }
            __builtin_amdgcn_s_setprio(0);
        }
        __syncthreads();   // implicit vmcnt(0): prefetch landed; buf[cur] free
        cur ^= 1;
    }

    // epilogue: merge half-row sums, normalize, write O (pairs of consecutive d)
    lsum += __shfl_xor(lsum, 32);
    float inv = 1.0f / lsum;
    short* Yrow = Y + (size_t)(b * T_ + qglob) * C_ + h * 128;
#pragma unroll
    for (int db = 0; db < 4; db++)
#pragma unroll
        for (int pr = 0; pr < 8; pr++) {
            unsigned u0 = (unsigned short)f2bf(oacc[db][2 * pr] * inv);
            unsigned u1 = (unsigned short)f2bf(oacc[db][2 * pr + 1] * inv);
            int d = db * 32 + ((2 * pr) & 3) + 8 * (pr >> 1) + 4 * hi;
            *(unsigned*)(Yrow + d) = u0 | (u1 << 16);
        }
}

extern "C" void kernel_launch(void* const* d_in, const int* in_sizes, int n_in,
                              void* d_out, int out_size, void* d_ws, size_t ws_size,
                              hipStream_t stream)
{
    const float* x      = (const float*)d_in[0];
    const float* fcos   = (const float*)d_in[1];
    const float* fsin   = (const float*)d_in[2];
    const float* W_attn = (const float*)d_in[3];
    const float* b_attn = (const float*)d_in[4];
    const float* W_proj = (const float*)d_in[5];
    const float* b_proj = (const float*)d_in[6];
    float* out = (float*)d_out;
    char* ws = (char*)d_ws;

    // workspace layout (92.3 MB, with dead-buffer aliasing)
    short* xb  = (short*)(ws + 0);          // 16,777,216
    float* qkv = (float*)(ws + 16777216);   // 50,331,648  [16777216 .. 67108864)
    short* y   = (short*)(ws + 16777216);   // alias qkv lower (qkv dead by then)
    short* WpT = (short*)(ws + 33554432);   // alias qkv upper, 8,388,608
    short* WaT = (short*)(ws + 67108864);   // 12,582,912
    short* Qb  = (short*)(ws + 67108864);   // alias WaT (dead after gemm1), 16,777,216
    short* Kb  = (short*)(ws + 83886080);   // 4,194,304
    short* VT  = (short*)(ws + 88080384);   // 4,194,304

    cast_bf16_kernel<<<4096, 256, 0, stream>>>(x, xb, NTOK_ * C_ / 8);
    transcast<<<dim3(32, 48), 256, 0, stream>>>(W_attn, WaT, C_, QKV_);
    gemm_bt<<<dim3(32, 24), 256, 0, stream>>>(xb, WaT, b_attn, qkv, NTOK_, QKV_, C_);
    rope_scatter<<<20480, 256, 0, stream>>>(qkv, fcos, fsin, Qb, Kb);
    v_transpose<<<dim3(32, 2, 8), 256, 0, stream>>>(qkv, VT);
    transcast<<<dim3(32, 32), 256, 0, stream>>>(W_proj, WpT, C_, C_);
    attn_kernel<<<dim3(32, 16), 256, 0, stream>>>(Qb, Kb, VT, y);
    gemm_bt<<<dim3(32, 16), 256, 0, stream>>>(y, WpT, b_proj, out, NTOK_, C_, C_);
}

// Round 13
// 208.310 us; speedup vs baseline: 1.0979x; 1.0750x over previous
//
#include <hip/hip_runtime.h>
#include <hip/hip_bf16.h>
#include <stdint.h>

#define B_ 2
#define T_ 2048
#define C_ 2048
#define NH_ 16
#define NKVH_ 4
#define HS_ 128
#define QKV_ 3072
#define NTOK_ 4096

typedef __attribute__((ext_vector_type(4))) float f32x4;
typedef __attribute__((ext_vector_type(16))) float f32x16;
typedef __attribute__((ext_vector_type(8))) short s16x8;

__device__ __forceinline__ short f2bf(float f) {
    union { float f; unsigned u; } v; v.f = f;
    unsigned r = v.u + 0x7FFFu + ((v.u >> 16) & 1u);
    return (short)(r >> 16);
}

__device__ __forceinline__ void async16(const void* g, void* l) {
    __builtin_amdgcn_global_load_lds(
        (const __attribute__((address_space(1))) void*)g,
        (__attribute__((address_space(3))) void*)l, 16, 0, 0);
}

// ---------------- cast x -> bf16 ----------------
__global__ void cast_bf16_kernel(const float* __restrict__ x, short* __restrict__ out, int n8) {
    int i = blockIdx.x * 256 + threadIdx.x;
    if (i >= n8) return;
    const float4* p = (const float4*)x + (size_t)i * 2;
    float4 a = p[0], b = p[1];
    short o[8] = { f2bf(a.x), f2bf(a.y), f2bf(a.z), f2bf(a.w),
                   f2bf(b.x), f2bf(b.y), f2bf(b.z), f2bf(b.w) };
    *(int4*)(out + (size_t)i * 8) = *(const int4*)o;
}

// ---------------- W [K][N] f32 -> WT [N][K] bf16 ----------------
__global__ void transcast(const float* __restrict__ W, short* __restrict__ WT, int Kd, int Nd) {
    __shared__ float tile[64][65];
    int k0 = blockIdx.x * 64, n0 = blockIdx.y * 64;
    int tid = threadIdx.x;
    int cl = tid & 63, rw = tid >> 6;
    for (int it = 0; it < 16; ++it) {
        int r = it * 4 + rw;
        tile[r][cl] = W[(size_t)(k0 + r) * Nd + n0 + cl];
    }
    __syncthreads();
    for (int it = 0; it < 16; ++it) {
        int n = it * 4 + rw;
        WT[(size_t)(n0 + n) * Kd + k0 + cl] = f2bf(tile[cl][n]);
    }
}

// ---------------- GEMM: A[M][K] bf16 x Bt[N][K] bf16 -> C[M][N] f32 + bias ----------------
__global__ __launch_bounds__(256, 2) void gemm_bt(
    const short* __restrict__ A, const short* __restrict__ Bt,
    const float* __restrict__ bias, float* __restrict__ Cc,
    int M, int N, int K)
{
    __shared__ short As[128 * 64];
    __shared__ short Bs[128 * 64];
    int tid = threadIdx.x;
    int w = tid >> 6, l = tid & 63;
    int lr = l & 15, lg = l >> 4;
    int bm = blockIdx.x, bn = blockIdx.y;
    int wm = (w >> 1) * 64, wn = (w & 1) * 64;
    f32x4 acc[4][4];
#pragma unroll
    for (int i = 0; i < 4; i++)
#pragma unroll
        for (int j = 0; j < 4; j++) { acc[i][j][0]=0.f; acc[i][j][1]=0.f; acc[i][j][2]=0.f; acc[i][j][3]=0.f; }
    int arow = l >> 3, acol = (l & 7) * 8;
    for (int k0 = 0; k0 < K; k0 += 64) {
#pragma unroll
        for (int i = 0; i < 4; i++) {
            int chunk = w * 4 + i;
            int row = chunk * 8 + arow;
            async16(A  + (size_t)(bm * 128 + row) * K + k0 + acol, (char*)As + chunk * 1024);
            async16(Bt + (size_t)(bn * 128 + row) * K + k0 + acol, (char*)Bs + chunk * 1024);
        }
        __syncthreads();
#pragma unroll
        for (int ks = 0; ks < 2; ks++) {
            s16x8 af[4], bf[4];
#pragma unroll
            for (int mi = 0; mi < 4; mi++)
                af[mi] = *(const s16x8*)&As[(wm + mi * 16 + lr) * 64 + ks * 32 + lg * 8];
#pragma unroll
            for (int ni = 0; ni < 4; ni++)
                bf[ni] = *(const s16x8*)&Bs[(wn + ni * 16 + lr) * 64 + ks * 32 + lg * 8];
#pragma unroll
            for (int mi = 0; mi < 4; mi++)
#pragma unroll
                for (int ni = 0; ni < 4; ni++)
                    acc[mi][ni] = __builtin_amdgcn_mfma_f32_16x16x32_bf16(af[mi], bf[ni], acc[mi][ni], 0, 0, 0);
        }
        __syncthreads();
    }
#pragma unroll
    for (int mi = 0; mi < 4; mi++) {
        int row = bm * 128 + wm + mi * 16 + lg * 4;
#pragma unroll
        for (int ni = 0; ni < 4; ni++) {
            int col = bn * 128 + wn + ni * 16 + lr;
            float bv = bias[col];
#pragma unroll
            for (int j = 0; j < 4; j++)
                Cc[(size_t)(row + j) * N + col] = acc[mi][ni][j] + bv;
        }
    }
}

// ---------------- Fused QKV GEMM: x_bf16 x W_attn^T + b, then RoPE + scatter in epilogue ----------
// Writes Q [B][NH][T][HS] bf16 (pre-scaled 1/sqrt(HS)), K [B][G][T][HS] bf16, VT [B][G][HS][T]
// bf16 DIRECTLY — the 50MB f32 qkv round-trip, rope_scatter and v_transpose are eliminated.
// Epilogue facts (from the proven gemm_bt layout): row = bm*128+wm+mi*16+lg*4+j,
// col = bn*128+wn+ni*16+lr -> region (Q: bn<16, K: 16..19, V: 20..23), head index and batch
// (b=bm>>4) are BLOCK-uniform; RoPE pairs (2i,2i+1) sit in lanes (l, l^1) -> one shfl_xor.
__global__ __launch_bounds__(256, 2) void gemm_qkv(
    const short* __restrict__ A, const short* __restrict__ Bt,
    const float* __restrict__ bias,
    const float* __restrict__ fcos, const float* __restrict__ fsin,
    short* __restrict__ Q, short* __restrict__ Kb, short* __restrict__ VT)
{
    __shared__ short As[128 * 64];
    __shared__ short Bs[128 * 64];
    const int K = C_;
    int tid = threadIdx.x;
    int w = tid >> 6, l = tid & 63;
    int lr = l & 15, lg = l >> 4;
    int bm = blockIdx.x, bn = blockIdx.y;
    int wm = (w >> 1) * 64, wn = (w & 1) * 64;
    f32x4 acc[4][4];
#pragma unroll
    for (int i = 0; i < 4; i++)
#pragma unroll
        for (int j = 0; j < 4; j++) { acc[i][j][0]=0.f; acc[i][j][1]=0.f; acc[i][j][2]=0.f; acc[i][j][3]=0.f; }
    int arow = l >> 3, acol = (l & 7) * 8;
    for (int k0 = 0; k0 < K; k0 += 64) {
#pragma unroll
        for (int i = 0; i < 4; i++) {
            int chunk = w * 4 + i;
            int row = chunk * 8 + arow;
            async16(A  + (size_t)(bm * 128 + row) * K + k0 + acol, (char*)As + chunk * 1024);
            async16(Bt + (size_t)(bn * 128 + row) * K + k0 + acol, (char*)Bs + chunk * 1024);
        }
        __syncthreads();
#pragma unroll
        for (int ks = 0; ks < 2; ks++) {
            s16x8 af[4], bf[4];
#pragma unroll
            for (int mi = 0; mi < 4; mi++)
                af[mi] = *(const s16x8*)&As[(wm + mi * 16 + lr) * 64 + ks * 32 + lg * 8];
#pragma unroll
            for (int ni = 0; ni < 4; ni++)
                bf[ni] = *(const s16x8*)&Bs[(wn + ni * 16 + lr) * 64 + ks * 32 + lg * 8];
#pragma unroll
            for (int mi = 0; mi < 4; mi++)
#pragma unroll
                for (int ni = 0; ni < 4; ni++)
                    acc[mi][ni] = __builtin_amdgcn_mfma_f32_16x16x32_bf16(af[mi], bf[ni], acc[mi][ni], 0, 0, 0);
        }
        __syncthreads();
    }
    // ---- fused epilogue ----
    int b = bm >> 4;                 // batch (block-uniform)
    int tt0 = (bm & 15) * 128 + wm;  // sequence pos base (+ mi*16 + lg*4 + j)
    const float qsc = 0.08838834764831845f; // 1/sqrt(128)
    if (bn < 20) {
        // Q (bn<16, h=bn) or K (g=bn-16): bias + RoPE + scatter [.,.][tt][d]
        bool isQ = (bn < 16);
        short* Ob = isQ ? (Q + (size_t)(b * NH_ + bn) * T_ * HS_)
                        : (Kb + (size_t)(b * NKVH_ + (bn - 16)) * T_ * HS_);
        float sc = isQ ? qsc : 1.0f;
#pragma unroll
        for (int ni = 0; ni < 4; ni++) {
            int d = wn + ni * 16 + lr;           // 0..127 within head
            int i = d >> 1;
            float ssign = (d & 1) ? 1.0f : -1.0f; // even lane: re*c - im*s ; odd: re*s + im*c
            float bv = bias[bn * 128 + d];
#pragma unroll
            for (int mi = 0; mi < 4; mi++) {
                int ttb = tt0 + mi * 16 + lg * 4;
#pragma unroll
                for (int j = 0; j < 4; j++) {
                    float v = acc[mi][ni][j] + bv;
                    float prt = __shfl_xor(v, 1);
                    int tt = ttb + j;
                    float c = fcos[tt * 64 + i], s = fsin[tt * 64 + i];
                    float outv = (v * c + ssign * prt * s) * sc;
                    Ob[(size_t)tt * HS_ + d] = f2bf(outv);
                }
            }
        }
    } else {
        // V (g=bn-20): bias + transpose-scatter VT[b][g][d][tt], 4 t packed per 8B write
        int g = bn - 20;
        short* Vb = VT + (size_t)(b * NKVH_ + g) * HS_ * T_;
#pragma unroll
        for (int ni = 0; ni < 4; ni++) {
            int d = wn + ni * 16 + lr;
            float bv = bias[bn * 128 + d];
#pragma unroll
            for (int mi = 0; mi < 4; mi++) {
                int ttb = tt0 + mi * 16 + lg * 4;
                short pk4[4];
#pragma unroll
                for (int j = 0; j < 4; j++) pk4[j] = f2bf(acc[mi][ni][j] + bv);
                *(int2*)(Vb + (size_t)d * T_ + ttb) = *(const int2*)pk4;
            }
        }
    }
}

// ---------------- Flash attention, causal GQA — swapped-QK^T 32x32 (round-12, unchanged) ----------
// grid: (B*NH=32 fast, 16 y). block: 256 (4 waves x 32 q-rows), ONE 128-row q-tile per block.
// qt = (y<8) ? y : 23-y (CU-complementary pairing). 2 blocks/CU co-resident (80KB LDS).
// Scheduling variants (LPT / intra-block pair / CU-pair) all land ~81us — per-tile VALU+stall
// is the plateau (VALUBusy 31.5% = 25.5us floor). Do not spend more rounds on scheduling.
// launch_bounds(256,2): (256,4) spills (round 2). grid.x MUST be 32 (b=bh>>4, round 3).
__global__ __launch_bounds__(256, 2) void attn_kernel(
    const short* __restrict__ Qg, const short* __restrict__ Kg,
    const short* __restrict__ VTg, short* __restrict__ Y)
{
    __shared__ short Ks[2][64 * 128];   // [buf][s][d], swizzled (256B rows, XOR (row&7)<<4)
    __shared__ short VTs[2][128 * 64];  // [buf][d][s], swizzled (128B rows, XOR (row&7)<<4)
    __shared__ short Ps[4][32 * 64];    // per-wave P: [q 32][s 64], swizzled 128B rows
    int tid = threadIdx.x, w = tid >> 6, l = tid & 63;
    int l31 = l & 31, hi = l >> 5;
    int yy = blockIdx.y;
    int qt = (yy < 8) ? yy : 23 - yy;   // CU-complementary pairing
    int bh = blockIdx.x;
    int b = bh >> 4, h = bh & 15, g = h >> 2;
    const short* Qb = Qg + (size_t)(b * NH_ + h) * T_ * HS_;
    const short* Kb = Kg + (size_t)(b * NKVH_ + g) * T_ * HS_;
    const short* Vb = VTg + (size_t)(b * NKVH_ + g) * HS_ * T_;

    auto STAGE = [&](int st, int buf) {
#pragma unroll
        for (int i = 0; i < 4; i++) {
            int chunk = w * 4 + i;
            int poff = chunk * 1024 + l * 16;
            int qoffk = poff ^ (((poff >> 8) & 7) << 4);
            async16(Kb + (size_t)(st * 64 + (qoffk >> 8)) * HS_ + ((qoffk & 255) >> 1),
                    (char*)&Ks[buf][0] + chunk * 1024);
            int qoffv = poff ^ (((poff >> 7) & 7) << 4);
            async16(Vb + (size_t)(qoffv >> 7) * T_ + st * 64 + ((qoffv & 127) >> 1),
                    (char*)&VTs[buf][0] + chunk * 1024);
        }
    };

    int qw = qt * 128 + w * 32;      // wave's first q-row
    int qglob = qw + l31;            // this lane's q-row

    s16x8 qf[8];
#pragma unroll
    for (int dc = 0; dc < 8; dc++)
        qf[dc] = *(const s16x8*)(Qb + (size_t)qglob * HS_ + dc * 16 + hi * 8);

    f32x16 oacc[4];
#pragma unroll
    for (int db = 0; db < 4; db++)
#pragma unroll
        for (int i = 0; i < 16; i++) oacc[db][i] = 0.f;
    float m = -1e30f, lsum = 0.f;
    int nst = 2 * qt + 2;

    STAGE(0, 0);
    __syncthreads();
    int cur = 0;

    for (int st = 0; st < nst; ++st) {
        if (st + 1 < nst) STAGE(st + 1, cur ^ 1);   // K+V prefetch flies under compute
        if (st * 64 <= qw) {                        // skip fully-masked tiles (wave-uniform)
            const char* KsC = (const char*)&Ks[cur][0];
            const char* VsC = (const char*)&VTs[cur][0];
            char* PsC = (char*)&Ps[w][0];

            f32x16 sacc[2];
            __builtin_amdgcn_s_setprio(1);
#pragma unroll
            for (int sb = 0; sb < 2; sb++) {
                f32x16 a0, a1;
#pragma unroll
                for (int i = 0; i < 16; i++) { a0[i] = 0.f; a1[i] = 0.f; }
#pragma unroll
                for (int dc = 0; dc < 4; dc++) {
                    int lo0 = (sb * 32 + l31) * 256 + dc * 32 + hi * 16;
                    int po0 = lo0 ^ (((lo0 >> 8) & 7) << 4);
                    s16x8 kf0 = *(const s16x8*)(KsC + po0);
                    a0 = __builtin_amdgcn_mfma_f32_32x32x16_bf16(kf0, qf[dc], a0, 0, 0, 0);
                    int lo1 = (sb * 32 + l31) * 256 + (dc + 4) * 32 + hi * 16;
                    int po1 = lo1 ^ (((lo1 >> 8) & 7) << 4);
                    s16x8 kf1 = *(const s16x8*)(KsC + po1);
                    a1 = __builtin_amdgcn_mfma_f32_32x32x16_bf16(kf1, qf[dc + 4], a1, 0, 0, 0);
                }
#pragma unroll
                for (int i = 0; i < 16; i++) a0[i] += a1[i];
                sacc[sb] = a0;
            }
            __builtin_amdgcn_s_setprio(0);
            if (st * 64 + 63 > qw) {
#pragma unroll
                for (int sb = 0; sb < 2; sb++)
#pragma unroll
                    for (int r = 0; r < 16; r++) {
                        int s = st * 64 + sb * 32 + (r & 3) + 8 * (r >> 2) + 4 * hi;
                        if (s > qglob) sacc[sb][r] = -1e30f;
                    }
            }
            float tm = -1e30f;
#pragma unroll
            for (int sb = 0; sb < 2; sb++)
#pragma unroll
                for (int r = 0; r < 16; r++) tm = fmaxf(tm, sacc[sb][r]);
            tm = fmaxf(tm, __shfl_xor(tm, 32));
            if (__any(tm > m)) {
                float mn = fmaxf(m, tm);
                float corr = __expf(m - mn);
                m = mn; lsum *= corr;
#pragma unroll
                for (int db = 0; db < 4; db++)
#pragma unroll
                    for (int r = 0; r < 16; r++) oacc[db][r] *= corr;
            }
#pragma unroll
            for (int sb = 0; sb < 2; sb++)
#pragma unroll
                for (int k = 0; k < 4; k++) {
                    float p0 = __expf(sacc[sb][4 * k]     - m);
                    float p1 = __expf(sacc[sb][4 * k + 1] - m);
                    float p2 = __expf(sacc[sb][4 * k + 2] - m);
                    float p3 = __expf(sacc[sb][4 * k + 3] - m);
                    lsum += (p0 + p1) + (p2 + p3);
                    unsigned w01 = (unsigned short)f2bf(p0) | ((unsigned)(unsigned short)f2bf(p1) << 16);
                    unsigned w23 = (unsigned short)f2bf(p2) | ((unsigned)(unsigned short)f2bf(p3) << 16);
                    uint2 pkv; pkv.x = w01; pkv.y = w23;
                    int sl = sb * 32 + 8 * k + 4 * hi;
                    int lo = l31 * 128 + sl * 2;
                    int po = lo ^ (((lo >> 7) & 7) << 4);
                    *(uint2*)(PsC + po) = pkv;
                }
            __builtin_amdgcn_s_setprio(1);
#pragma unroll
            for (int sc = 0; sc < 4; sc++) {
                unsigned ptmp[4];
                int lp = l31 * 128 + sc * 32 + hi * 16;
                int pp = lp ^ (((lp >> 7) & 7) << 4);
                *(uint2*)&ptmp[0] = *(const uint2*)(PsC + pp);
                *(uint2*)&ptmp[2] = *(const uint2*)(PsC + pp + 8);
                s16x8 pf = *(const s16x8*)ptmp;
#pragma unroll
                for (int db = 0; db < 4; db++) {
                    int lo = (db * 32 + l31) * 128 + sc * 32 + hi * 16;
                    int po = lo ^ (((lo >> 7) & 7) << 4);
                    s16x8 vf = *(const s16x8*)(VsC + po);
                    oacc[db] = __builtin_amdgcn_mfma_f32_32x32x16_bf16(vf, pf, oacc[db], 0, 0, 0);
                }
            }
            __builtin_amdgcn_s_setprio(0);
        }
        __syncthreads();
        cur ^= 1;
    }

    lsum += __shfl_xor(lsum, 32);
    float inv = 1.0f / lsum;
    short* Yrow = Y + (size_t)(b * T_ + qglob) * C_ + h * 128;
#pragma unroll
    for (int db = 0; db < 4; db++)
#pragma unroll
        for (int pr = 0; pr < 8; pr++) {
            unsigned u0 = (unsigned short)f2bf(oacc[db][2 * pr] * inv);
            unsigned u1 = (unsigned short)f2bf(oacc[db][2 * pr + 1] * inv);
            int d = db * 32 + ((2 * pr) & 3) + 8 * (pr >> 1) + 4 * hi;
            *(unsigned*)(Yrow + d) = u0 | (u1 << 16);
        }
}

extern "C" void kernel_launch(void* const* d_in, const int* in_sizes, int n_in,
                              void* d_out, int out_size, void* d_ws, size_t ws_size,
                              hipStream_t stream)
{
    const float* x      = (const float*)d_in[0];
    const float* fcos   = (const float*)d_in[1];
    const float* fsin   = (const float*)d_in[2];
    const float* W_attn = (const float*)d_in[3];
    const float* b_attn = (const float*)d_in[4];
    const float* W_proj = (const float*)d_in[5];
    const float* b_proj = (const float*)d_in[6];
    float* out = (float*)d_out;
    char* ws = (char*)d_ws;

    // workspace layout (79.7 MB, no aliasing — qkv f32 buffer eliminated)
    short* xb  = (short*)(ws + 0);          // 16,777,216
    short* y   = (short*)(ws + 16777216);   // 16,777,216
    short* WpT = (short*)(ws + 33554432);   //  8,388,608
    short* Qb  = (short*)(ws + 41943040);   // 16,777,216
    short* Kb  = (short*)(ws + 58720256);   //  4,194,304
    short* VT  = (short*)(ws + 62914560);   //  4,194,304
    short* WaT = (short*)(ws + 67108864);   // 12,582,912

    cast_bf16_kernel<<<4096, 256, 0, stream>>>(x, xb, NTOK_ * C_ / 8);
    transcast<<<dim3(32, 48), 256, 0, stream>>>(W_attn, WaT, C_, QKV_);
    gemm_qkv<<<dim3(32, 24), 256, 0, stream>>>(xb, WaT, b_attn, fcos, fsin, Qb, Kb, VT);
    transcast<<<dim3(32, 32), 256, 0, stream>>>(W_proj, WpT, C_, C_);
    attn_kernel<<<dim3(32, 16), 256, 0, stream>>>(Qb, Kb, VT, y);
    gemm_bt<<<dim3(32, 16), 256, 0, stream>>>(y, WpT, b_proj, out, NTOK_, C_, C_);
}

// Round 14
// 208.259 us; speedup vs baseline: 1.0982x; 1.0002x over previous
//
#include <hip/hip_runtime.h>
#include <hip/hip_bf16.h>
#include <stdint.h>

#define B_ 2
#define T_ 2048
#define C_ 2048
#define NH_ 16
#define NKVH_ 4
#define HS_ 128
#define QKV_ 3072
#define NTOK_ 4096

typedef __attribute__((ext_vector_type(4))) float f32x4;
typedef __attribute__((ext_vector_type(16))) float f32x16;
typedef __attribute__((ext_vector_type(8))) short s16x8;

__device__ __forceinline__ short f2bf(float f) {
    union { float f; unsigned u; } v; v.f = f;
    unsigned r = v.u + 0x7FFFu + ((v.u >> 16) & 1u);
    return (short)(r >> 16);
}

__device__ __forceinline__ void async16(const void* g, void* l) {
    __builtin_amdgcn_global_load_lds(
        (const __attribute__((address_space(1))) void*)g,
        (__attribute__((address_space(3))) void*)l, 16, 0, 0);
}

// ---------------- cast x -> bf16 (64B/thread) ----------------
__global__ void cast_bf16_kernel(const float* __restrict__ x, short* __restrict__ out, int n8) {
    int i0 = blockIdx.x * 512 + threadIdx.x;
#pragma unroll
    for (int rep = 0; rep < 2; rep++) {
        int i = i0 + rep * 256;
        if (i >= n8) return;
        const float4* p = (const float4*)x + (size_t)i * 2;
        float4 a = p[0], b = p[1];
        short o[8] = { f2bf(a.x), f2bf(a.y), f2bf(a.z), f2bf(a.w),
                       f2bf(b.x), f2bf(b.y), f2bf(b.z), f2bf(b.w) };
        *(int4*)(out + (size_t)i * 8) = *(const int4*)o;
    }
}

// ---------------- W [K][N] f32 -> WT [N][K] bf16, vectorized ----------------
// Load: float4 per lane (16B), 16 rows/pass x 4 passes. Banks: (r + 4c)%32, 2-way max (free).
// Write: lane = 16*nr + kq handles 4 consecutive k of one n-row -> int2 (8B) packed bf16.
// Banks on transposed read (pad 65): (4kq + j + n)%32 -> 2-way max.
__global__ void transcast(const float* __restrict__ W, short* __restrict__ WT, int Kd, int Nd) {
    __shared__ float tile[64][65];
    int k0 = blockIdx.x * 64, n0 = blockIdx.y * 64;
    int tid = threadIdx.x;
    int rr = tid >> 4, cc = tid & 15;       // load: row group, float4 col
#pragma unroll
    for (int ps = 0; ps < 4; ++ps) {
        int r = ps * 16 + rr;
        float4 v = *(const float4*)(W + (size_t)(k0 + r) * Nd + n0 + 4 * cc);
        tile[r][4 * cc + 0] = v.x;
        tile[r][4 * cc + 1] = v.y;
        tile[r][4 * cc + 2] = v.z;
        tile[r][4 * cc + 3] = v.w;
    }
    __syncthreads();
    int l = tid & 63, w4 = tid >> 6;        // write: 4 lanes-groups
    int kq = l & 15, nr = l >> 4;           // k-quad 0..15, n-subrow 0..3
#pragma unroll
    for (int ps = 0; ps < 4; ++ps) {
        int n = (w4 * 4 + ps) * 4 + nr;     // 64 n-rows total
        short pk4[4];
#pragma unroll
        for (int j = 0; j < 4; ++j) pk4[j] = f2bf(tile[4 * kq + j][n]);
        *(int2*)(WT + (size_t)(n0 + n) * Kd + k0 + 4 * kq) = *(const int2*)pk4;
    }
}

// ---------------- GEMM: A[M][K] bf16 x Bt[N][K] bf16 -> C[M][N] f32 + bias ----------------
__global__ __launch_bounds__(256, 2) void gemm_bt(
    const short* __restrict__ A, const short* __restrict__ Bt,
    const float* __restrict__ bias, float* __restrict__ Cc,
    int M, int N, int K)
{
    __shared__ short As[128 * 64];
    __shared__ short Bs[128 * 64];
    int tid = threadIdx.x;
    int w = tid >> 6, l = tid & 63;
    int lr = l & 15, lg = l >> 4;
    int bm = blockIdx.x, bn = blockIdx.y;
    int wm = (w >> 1) * 64, wn = (w & 1) * 64;
    f32x4 acc[4][4];
#pragma unroll
    for (int i = 0; i < 4; i++)
#pragma unroll
        for (int j = 0; j < 4; j++) { acc[i][j][0]=0.f; acc[i][j][1]=0.f; acc[i][j][2]=0.f; acc[i][j][3]=0.f; }
    int arow = l >> 3, acol = (l & 7) * 8;
    for (int k0 = 0; k0 < K; k0 += 64) {
#pragma unroll
        for (int i = 0; i < 4; i++) {
            int chunk = w * 4 + i;
            int row = chunk * 8 + arow;
            async16(A  + (size_t)(bm * 128 + row) * K + k0 + acol, (char*)As + chunk * 1024);
            async16(Bt + (size_t)(bn * 128 + row) * K + k0 + acol, (char*)Bs + chunk * 1024);
        }
        __syncthreads();
#pragma unroll
        for (int ks = 0; ks < 2; ks++) {
            s16x8 af[4], bf[4];
#pragma unroll
            for (int mi = 0; mi < 4; mi++)
                af[mi] = *(const s16x8*)&As[(wm + mi * 16 + lr) * 64 + ks * 32 + lg * 8];
#pragma unroll
            for (int ni = 0; ni < 4; ni++)
                bf[ni] = *(const s16x8*)&Bs[(wn + ni * 16 + lr) * 64 + ks * 32 + lg * 8];
#pragma unroll
            for (int mi = 0; mi < 4; mi++)
#pragma unroll
                for (int ni = 0; ni < 4; ni++)
                    acc[mi][ni] = __builtin_amdgcn_mfma_f32_16x16x32_bf16(af[mi], bf[ni], acc[mi][ni], 0, 0, 0);
        }
        __syncthreads();
    }
#pragma unroll
    for (int mi = 0; mi < 4; mi++) {
        int row = bm * 128 + wm + mi * 16 + lg * 4;
#pragma unroll
        for (int ni = 0; ni < 4; ni++) {
            int col = bn * 128 + wn + ni * 16 + lr;
            float bv = bias[col];
#pragma unroll
            for (int j = 0; j < 4; j++)
                Cc[(size_t)(row + j) * N + col] = acc[mi][ni][j] + bv;
        }
    }
}

// ---------------- Fused QKV GEMM: x_bf16 x W_attn^T + b, then RoPE + scatter in epilogue ----------
// Writes Q [B][NH][T][HS] bf16 (pre-scaled 1/sqrt(HS)), K [B][G][T][HS] bf16, VT [B][G][HS][T]
// bf16 DIRECTLY — the 50MB f32 qkv round-trip, rope_scatter and v_transpose are eliminated.
__global__ __launch_bounds__(256, 2) void gemm_qkv(
    const short* __restrict__ A, const short* __restrict__ Bt,
    const float* __restrict__ bias,
    const float* __restrict__ fcos, const float* __restrict__ fsin,
    short* __restrict__ Q, short* __restrict__ Kb, short* __restrict__ VT)
{
    __shared__ short As[128 * 64];
    __shared__ short Bs[128 * 64];
    const int K = C_;
    int tid = threadIdx.x;
    int w = tid >> 6, l = tid & 63;
    int lr = l & 15, lg = l >> 4;
    int bm = blockIdx.x, bn = blockIdx.y;
    int wm = (w >> 1) * 64, wn = (w & 1) * 64;
    f32x4 acc[4][4];
#pragma unroll
    for (int i = 0; i < 4; i++)
#pragma unroll
        for (int j = 0; j < 4; j++) { acc[i][j][0]=0.f; acc[i][j][1]=0.f; acc[i][j][2]=0.f; acc[i][j][3]=0.f; }
    int arow = l >> 3, acol = (l & 7) * 8;
    for (int k0 = 0; k0 < K; k0 += 64) {
#pragma unroll
        for (int i = 0; i < 4; i++) {
            int chunk = w * 4 + i;
            int row = chunk * 8 + arow;
            async16(A  + (size_t)(bm * 128 + row) * K + k0 + acol, (char*)As + chunk * 1024);
            async16(Bt + (size_t)(bn * 128 + row) * K + k0 + acol, (char*)Bs + chunk * 1024);
        }
        __syncthreads();
#pragma unroll
        for (int ks = 0; ks < 2; ks++) {
            s16x8 af[4], bf[4];
#pragma unroll
            for (int mi = 0; mi < 4; mi++)
                af[mi] = *(const s16x8*)&As[(wm + mi * 16 + lr) * 64 + ks * 32 + lg * 8];
#pragma unroll
            for (int ni = 0; ni < 4; ni++)
                bf[ni] = *(const s16x8*)&Bs[(wn + ni * 16 + lr) * 64 + ks * 32 + lg * 8];
#pragma unroll
            for (int mi = 0; mi < 4; mi++)
#pragma unroll
                for (int ni = 0; ni < 4; ni++)
                    acc[mi][ni] = __builtin_amdgcn_mfma_f32_16x16x32_bf16(af[mi], bf[ni], acc[mi][ni], 0, 0, 0);
        }
        __syncthreads();
    }
    // ---- fused epilogue ----
    int b = bm >> 4;                 // batch (block-uniform)
    int tt0 = (bm & 15) * 128 + wm;  // sequence pos base (+ mi*16 + lg*4 + j)
    const float qsc = 0.08838834764831845f; // 1/sqrt(128)
    if (bn < 20) {
        bool isQ = (bn < 16);
        short* Ob = isQ ? (Q + (size_t)(b * NH_ + bn) * T_ * HS_)
                        : (Kb + (size_t)(b * NKVH_ + (bn - 16)) * T_ * HS_);
        float sc = isQ ? qsc : 1.0f;
#pragma unroll
        for (int ni = 0; ni < 4; ni++) {
            int d = wn + ni * 16 + lr;           // 0..127 within head
            int i = d >> 1;
            float ssign = (d & 1) ? 1.0f : -1.0f;
            float bv = bias[bn * 128 + d];
#pragma unroll
            for (int mi = 0; mi < 4; mi++) {
                int ttb = tt0 + mi * 16 + lg * 4;
#pragma unroll
                for (int j = 0; j < 4; j++) {
                    float v = acc[mi][ni][j] + bv;
                    float prt = __shfl_xor(v, 1);
                    int tt = ttb + j;
                    float c = fcos[tt * 64 + i], s = fsin[tt * 64 + i];
                    float outv = (v * c + ssign * prt * s) * sc;
                    Ob[(size_t)tt * HS_ + d] = f2bf(outv);
                }
            }
        }
    } else {
        int g = bn - 20;
        short* Vb = VT + (size_t)(b * NKVH_ + g) * HS_ * T_;
#pragma unroll
        for (int ni = 0; ni < 4; ni++) {
            int d = wn + ni * 16 + lr;
            float bv = bias[bn * 128 + d];
#pragma unroll
            for (int mi = 0; mi < 4; mi++) {
                int ttb = tt0 + mi * 16 + lg * 4;
                short pk4[4];
#pragma unroll
                for (int j = 0; j < 4; j++) pk4[j] = f2bf(acc[mi][ni][j] + bv);
                *(int2*)(Vb + (size_t)d * T_ + ttb) = *(const int2*)pk4;
            }
        }
    }
}

// ---------------- Flash attention, causal GQA — swapped-QK^T 32x32 (round-12, unchanged) ----------
// ~81us plateau: per-tile cost, not scheduling (LPT / intra-block pair / CU-pair all null).
// Split-KV would also be null: round-12 measured its end-state (balanced 34 units/CU, 2
// co-resident -> 81us). Further gains need per-tile pipeline depth, not block scheduling.
// launch_bounds(256,2): (256,4) spills (round 2). grid.x MUST be 32 (b=bh>>4, round 3).
__global__ __launch_bounds__(256, 2) void attn_kernel(
    const short* __restrict__ Qg, const short* __restrict__ Kg,
    const short* __restrict__ VTg, short* __restrict__ Y)
{
    __shared__ short Ks[2][64 * 128];   // [buf][s][d], swizzled (256B rows, XOR (row&7)<<4)
    __shared__ short VTs[2][128 * 64];  // [buf][d][s], swizzled (128B rows, XOR (row&7)<<4)
    __shared__ short Ps[4][32 * 64];    // per-wave P: [q 32][s 64], swizzled 128B rows
    int tid = threadIdx.x, w = tid >> 6, l = tid & 63;
    int l31 = l & 31, hi = l >> 5;
    int yy = blockIdx.y;
    int qt = (yy < 8) ? yy : 23 - yy;   // CU-complementary pairing
    int bh = blockIdx.x;
    int b = bh >> 4, h = bh & 15, g = h >> 2;
    const short* Qb = Qg + (size_t)(b * NH_ + h) * T_ * HS_;
    const short* Kb = Kg + (size_t)(b * NKVH_ + g) * T_ * HS_;
    const short* Vb = VTg + (size_t)(b * NKVH_ + g) * HS_ * T_;

    auto STAGE = [&](int st, int buf) {
#pragma unroll
        for (int i = 0; i < 4; i++) {
            int chunk = w * 4 + i;
            int poff = chunk * 1024 + l * 16;
            int qoffk = poff ^ (((poff >> 8) & 7) << 4);
            async16(Kb + (size_t)(st * 64 + (qoffk >> 8)) * HS_ + ((qoffk & 255) >> 1),
                    (char*)&Ks[buf][0] + chunk * 1024);
            int qoffv = poff ^ (((poff >> 7) & 7) << 4);
            async16(Vb + (size_t)(qoffv >> 7) * T_ + st * 64 + ((qoffv & 127) >> 1),
                    (char*)&VTs[buf][0] + chunk * 1024);
        }
    };

    int qw = qt * 128 + w * 32;      // wave's first q-row
    int qglob = qw + l31;            // this lane's q-row

    s16x8 qf[8];
#pragma unroll
    for (int dc = 0; dc < 8; dc++)
        qf[dc] = *(const s16x8*)(Qb + (size_t)qglob * HS_ + dc * 16 + hi * 8);

    f32x16 oacc[4];
#pragma unroll
    for (int db = 0; db < 4; db++)
#pragma unroll
        for (int i = 0; i < 16; i++) oacc[db][i] = 0.f;
    float m = -1e30f, lsum = 0.f;
    int nst = 2 * qt + 2;

    STAGE(0, 0);
    __syncthreads();
    int cur = 0;

    for (int st = 0; st < nst; ++st) {
        if (st + 1 < nst) STAGE(st + 1, cur ^ 1);   // K+V prefetch flies under compute
        if (st * 64 <= qw) {                        // skip fully-masked tiles (wave-uniform)
            const char* KsC = (const char*)&Ks[cur][0];
            const char* VsC = (const char*)&VTs[cur][0];
            char* PsC = (char*)&Ps[w][0];

            f32x16 sacc[2];
            __builtin_amdgcn_s_setprio(1);
#pragma unroll
            for (int sb = 0; sb < 2; sb++) {
                f32x16 a0, a1;
#pragma unroll
                for (int i = 0; i < 16; i++) { a0[i] = 0.f; a1[i] = 0.f; }
#pragma unroll
                for (int dc = 0; dc < 4; dc++) {
                    int lo0 = (sb * 32 + l31) * 256 + dc * 32 + hi * 16;
                    int po0 = lo0 ^ (((lo0 >> 8) & 7) << 4);
                    s16x8 kf0 = *(const s16x8*)(KsC + po0);
                    a0 = __builtin_amdgcn_mfma_f32_32x32x16_bf16(kf0, qf[dc], a0, 0, 0, 0);
                    int lo1 = (sb * 32 + l31) * 256 + (dc + 4) * 32 + hi * 16;
                    int po1 = lo1 ^ (((lo1 >> 8) & 7) << 4);
                    s16x8 kf1 = *(const s16x8*)(KsC + po1);
                    a1 = __builtin_amdgcn_mfma_f32_32x32x16_bf16(kf1, qf[dc + 4], a1, 0, 0, 0);
                }
#pragma unroll
                for (int i = 0; i < 16; i++) a0[i] += a1[i];
                sacc[sb] = a0;
            }
            __builtin_amdgcn_s_setprio(0);
            if (st * 64 + 63 > qw) {
#pragma unroll
                for (int sb = 0; sb < 2; sb++)
#pragma unroll
                    for (int r = 0; r < 16; r++) {
                        int s = st * 64 + sb * 32 + (r & 3) + 8 * (r >> 2) + 4 * hi;
                        if (s > qglob) sacc[sb][r] = -1e30f;
                    }
            }
            float tm = -1e30f;
#pragma unroll
            for (int sb = 0; sb < 2; sb++)
#pragma unroll
                for (int r = 0; r < 16; r++) tm = fmaxf(tm, sacc[sb][r]);
            tm = fmaxf(tm, __shfl_xor(tm, 32));
            if (__any(tm > m)) {
                float mn = fmaxf(m, tm);
                float corr = __expf(m - mn);
                m = mn; lsum *= corr;
#pragma unroll
                for (int db = 0; db < 4; db++)
#pragma unroll
                    for (int r = 0; r < 16; r++) oacc[db][r] *= corr;
            }
#pragma unroll
            for (int sb = 0; sb < 2; sb++)
#pragma unroll
                for (int k = 0; k < 4; k++) {
                    float p0 = __expf(sacc[sb][4 * k]     - m);
                    float p1 = __expf(sacc[sb][4 * k + 1] - m);
                    float p2 = __expf(sacc[sb][4 * k + 2] - m);
                    float p3 = __expf(sacc[sb][4 * k + 3] - m);
                    lsum += (p0 + p1) + (p2 + p3);
                    unsigned w01 = (unsigned short)f2bf(p0) | ((unsigned)(unsigned short)f2bf(p1) << 16);
                    unsigned w23 = (unsigned short)f2bf(p2) | ((unsigned)(unsigned short)f2bf(p3) << 16);
                    uint2 pkv; pkv.x = w01; pkv.y = w23;
                    int sl = sb * 32 + 8 * k + 4 * hi;
                    int lo = l31 * 128 + sl * 2;
                    int po = lo ^ (((lo >> 7) & 7) << 4);
                    *(uint2*)(PsC + po) = pkv;
                }
            __builtin_amdgcn_s_setprio(1);
#pragma unroll
            for (int sc = 0; sc < 4; sc++) {
                unsigned ptmp[4];
                int lp = l31 * 128 + sc * 32 + hi * 16;
                int pp = lp ^ (((lp >> 7) & 7) << 4);
                *(uint2*)&ptmp[0] = *(const uint2*)(PsC + pp);
                *(uint2*)&ptmp[2] = *(const uint2*)(PsC + pp + 8);
                s16x8 pf = *(const s16x8*)ptmp;
#pragma unroll
                for (int db = 0; db < 4; db++) {
                    int lo = (db * 32 + l31) * 128 + sc * 32 + hi * 16;
                    int po = lo ^ (((lo >> 7) & 7) << 4);
                    s16x8 vf = *(const s16x8*)(VsC + po);
                    oacc[db] = __builtin_amdgcn_mfma_f32_32x32x16_bf16(vf, pf, oacc[db], 0, 0, 0);
                }
            }
            __builtin_amdgcn_s_setprio(0);
        }
        __syncthreads();
        cur ^= 1;
    }

    lsum += __shfl_xor(lsum, 32);
    float inv = 1.0f / lsum;
    short* Yrow = Y + (size_t)(b * T_ + qglob) * C_ + h * 128;
#pragma unroll
    for (int db = 0; db < 4; db++)
#pragma unroll
        for (int pr = 0; pr < 8; pr++) {
            unsigned u0 = (unsigned short)f2bf(oacc[db][2 * pr] * inv);
            unsigned u1 = (unsigned short)f2bf(oacc[db][2 * pr + 1] * inv);
            int d = db * 32 + ((2 * pr) & 3) + 8 * (pr >> 1) + 4 * hi;
            *(unsigned*)(Yrow + d) = u0 | (u1 << 16);
        }
}

extern "C" void kernel_launch(void* const* d_in, const int* in_sizes, int n_in,
                              void* d_out, int out_size, void* d_ws, size_t ws_size,
                              hipStream_t stream)
{
    const float* x      = (const float*)d_in[0];
    const float* fcos   = (const float*)d_in[1];
    const float* fsin   = (const float*)d_in[2];
    const float* W_attn = (const float*)d_in[3];
    const float* b_attn = (const float*)d_in[4];
    const float* W_proj = (const float*)d_in[5];
    const float* b_proj = (const float*)d_in[6];
    float* out = (float*)d_out;
    char* ws = (char*)d_ws;

    // workspace layout (79.7 MB, no aliasing — qkv f32 buffer eliminated)
    short* xb  = (short*)(ws + 0);          // 16,777,216
    short* y   = (short*)(ws + 16777216);   // 16,777,216
    short* WpT = (short*)(ws + 33554432);   //  8,388,608
    short* Qb  = (short*)(ws + 41943040);   // 16,777,216
    short* Kb  = (short*)(ws + 58720256);   //  4,194,304
    short* VT  = (short*)(ws + 62914560);   //  4,194,304
    short* WaT = (short*)(ws + 67108864);   // 12,582,912

    cast_bf16_kernel<<<2048, 256, 0, stream>>>(x, xb, NTOK_ * C_ / 8);
    transcast<<<dim3(32, 48), 256, 0, stream>>>(W_attn, WaT, C_, QKV_);
    gemm_qkv<<<dim3(32, 24), 256, 0, stream>>>(xb, WaT, b_attn, fcos, fsin, Qb, Kb, VT);
    transcast<<<dim3(32, 32), 256, 0, stream>>>(W_proj, WpT, C_, C_);
    attn_kernel<<<dim3(32, 16), 256, 0, stream>>>(Qb, Kb, VT, y);
    gemm_bt<<<dim3(32, 16), 256, 0, stream>>>(y, WpT, b_proj, out, NTOK_, C_, C_);
}

// Round 15
// 203.480 us; speedup vs baseline: 1.1240x; 1.0235x over previous
//
#include <hip/hip_runtime.h>
#include <hip/hip_bf16.h>
#include <stdint.h>

#define B_ 2
#define T_ 2048
#define C_ 2048
#define NH_ 16
#define NKVH_ 4
#define HS_ 128
#define QKV_ 3072
#define NTOK_ 4096

typedef __attribute__((ext_vector_type(4))) float f32x4;
typedef __attribute__((ext_vector_type(16))) float f32x16;
typedef __attribute__((ext_vector_type(8))) short s16x8;

__device__ __forceinline__ short f2bf(float f) {
    union { float f; unsigned u; } v; v.f = f;
    unsigned r = v.u + 0x7FFFu + ((v.u >> 16) & 1u);
    return (short)(r >> 16);
}

__device__ __forceinline__ void async16(const void* g, void* l) {
    __builtin_amdgcn_global_load_lds(
        (const __attribute__((address_space(1))) void*)g,
        (__attribute__((address_space(3))) void*)l, 16, 0, 0);
}

// ---------------- fused prep: cast x->bf16 + transcast W_attn + transcast W_proj ----------------
// One launch instead of three (round-14 lesson: prep is launch/latency-bound, not BW-bound).
__device__ __forceinline__ void transcast_body(const float* __restrict__ W, short* __restrict__ WT,
                                               int Kd, int Nd, int k0, int n0, int tid) {
    __shared__ float tile[64][65];
    int cl = tid & 63, rw = tid >> 6;
    for (int it = 0; it < 16; ++it) {
        int r = it * 4 + rw;
        tile[r][cl] = W[(size_t)(k0 + r) * Nd + n0 + cl];
    }
    __syncthreads();
    for (int it = 0; it < 16; ++it) {
        int n = it * 4 + rw;
        WT[(size_t)(n0 + n) * Kd + k0 + cl] = f2bf(tile[cl][n]);
    }
}

__global__ void prep_kernel(const float* __restrict__ x, short* __restrict__ xb,
                            const float* __restrict__ Wa, short* __restrict__ WaT,
                            const float* __restrict__ Wp, short* __restrict__ WpT)
{
    int bid = blockIdx.x, tid = threadIdx.x;
    if (bid < 2048) {
        const int n8 = NTOK_ * C_ / 8;
        int i0 = bid * 512 + tid;
#pragma unroll
        for (int rep = 0; rep < 2; rep++) {
            int i = i0 + rep * 256;
            if (i >= n8) return;
            const float4* p = (const float4*)x + (size_t)i * 2;
            float4 a = p[0], b = p[1];
            short o[8] = { f2bf(a.x), f2bf(a.y), f2bf(a.z), f2bf(a.w),
                           f2bf(b.x), f2bf(b.y), f2bf(b.z), f2bf(b.w) };
            *(int4*)(xb + (size_t)i * 8) = *(const int4*)o;
        }
    } else if (bid < 3584) {
        int b2 = bid - 2048;                 // 1536 blocks = 32 x 48
        transcast_body(Wa, WaT, C_, QKV_, (b2 & 31) * 64, (b2 >> 5) * 64, tid);
    } else {
        int b2 = bid - 3584;                 // 1024 blocks = 32 x 32
        transcast_body(Wp, WpT, C_, C_, (b2 & 31) * 64, (b2 >> 5) * 64, tid);
    }
}

// ---------------- GEMM: A[M][K] bf16 x Bt[N][K] bf16 -> C[M][N] f32 + bias ----------------
__global__ __launch_bounds__(256, 2) void gemm_bt(
    const short* __restrict__ A, const short* __restrict__ Bt,
    const float* __restrict__ bias, float* __restrict__ Cc,
    int M, int N, int K)
{
    __shared__ short As[128 * 64];
    __shared__ short Bs[128 * 64];
    int tid = threadIdx.x;
    int w = tid >> 6, l = tid & 63;
    int lr = l & 15, lg = l >> 4;
    int bm = blockIdx.x, bn = blockIdx.y;
    int wm = (w >> 1) * 64, wn = (w & 1) * 64;
    f32x4 acc[4][4];
#pragma unroll
    for (int i = 0; i < 4; i++)
#pragma unroll
        for (int j = 0; j < 4; j++) { acc[i][j][0]=0.f; acc[i][j][1]=0.f; acc[i][j][2]=0.f; acc[i][j][3]=0.f; }
    int arow = l >> 3, acol = (l & 7) * 8;
    for (int k0 = 0; k0 < K; k0 += 64) {
#pragma unroll
        for (int i = 0; i < 4; i++) {
            int chunk = w * 4 + i;
            int row = chunk * 8 + arow;
            async16(A  + (size_t)(bm * 128 + row) * K + k0 + acol, (char*)As + chunk * 1024);
            async16(Bt + (size_t)(bn * 128 + row) * K + k0 + acol, (char*)Bs + chunk * 1024);
        }
        __syncthreads();
#pragma unroll
        for (int ks = 0; ks < 2; ks++) {
            s16x8 af[4], bf[4];
#pragma unroll
            for (int mi = 0; mi < 4; mi++)
                af[mi] = *(const s16x8*)&As[(wm + mi * 16 + lr) * 64 + ks * 32 + lg * 8];
#pragma unroll
            for (int ni = 0; ni < 4; ni++)
                bf[ni] = *(const s16x8*)&Bs[(wn + ni * 16 + lr) * 64 + ks * 32 + lg * 8];
#pragma unroll
            for (int mi = 0; mi < 4; mi++)
#pragma unroll
                for (int ni = 0; ni < 4; ni++)
                    acc[mi][ni] = __builtin_amdgcn_mfma_f32_16x16x32_bf16(af[mi], bf[ni], acc[mi][ni], 0, 0, 0);
        }
        __syncthreads();
    }
#pragma unroll
    for (int mi = 0; mi < 4; mi++) {
        int row = bm * 128 + wm + mi * 16 + lg * 4;
#pragma unroll
        for (int ni = 0; ni < 4; ni++) {
            int col = bn * 128 + wn + ni * 16 + lr;
            float bv = bias[col];
#pragma unroll
            for (int j = 0; j < 4; j++)
                Cc[(size_t)(row + j) * N + col] = acc[mi][ni][j] + bv;
        }
    }
}

// ---------------- Fused QKV GEMM: x_bf16 x W_attn^T + b, then RoPE + scatter in epilogue ----------
__global__ __launch_bounds__(256, 2) void gemm_qkv(
    const short* __restrict__ A, const short* __restrict__ Bt,
    const float* __restrict__ bias,
    const float* __restrict__ fcos, const float* __restrict__ fsin,
    short* __restrict__ Q, short* __restrict__ Kb, short* __restrict__ VT)
{
    __shared__ short As[128 * 64];
    __shared__ short Bs[128 * 64];
    const int K = C_;
    int tid = threadIdx.x;
    int w = tid >> 6, l = tid & 63;
    int lr = l & 15, lg = l >> 4;
    int bm = blockIdx.x, bn = blockIdx.y;
    int wm = (w >> 1) * 64, wn = (w & 1) * 64;
    f32x4 acc[4][4];
#pragma unroll
    for (int i = 0; i < 4; i++)
#pragma unroll
        for (int j = 0; j < 4; j++) { acc[i][j][0]=0.f; acc[i][j][1]=0.f; acc[i][j][2]=0.f; acc[i][j][3]=0.f; }
    int arow = l >> 3, acol = (l & 7) * 8;
    for (int k0 = 0; k0 < K; k0 += 64) {
#pragma unroll
        for (int i = 0; i < 4; i++) {
            int chunk = w * 4 + i;
            int row = chunk * 8 + arow;
            async16(A  + (size_t)(bm * 128 + row) * K + k0 + acol, (char*)As + chunk * 1024);
            async16(Bt + (size_t)(bn * 128 + row) * K + k0 + acol, (char*)Bs + chunk * 1024);
        }
        __syncthreads();
#pragma unroll
        for (int ks = 0; ks < 2; ks++) {
            s16x8 af[4], bf[4];
#pragma unroll
            for (int mi = 0; mi < 4; mi++)
                af[mi] = *(const s16x8*)&As[(wm + mi * 16 + lr) * 64 + ks * 32 + lg * 8];
#pragma unroll
            for (int ni = 0; ni < 4; ni++)
                bf[ni] = *(const s16x8*)&Bs[(wn + ni * 16 + lr) * 64 + ks * 32 + lg * 8];
#pragma unroll
            for (int mi = 0; mi < 4; mi++)
#pragma unroll
                for (int ni = 0; ni < 4; ni++)
                    acc[mi][ni] = __builtin_amdgcn_mfma_f32_16x16x32_bf16(af[mi], bf[ni], acc[mi][ni], 0, 0, 0);
        }
        __syncthreads();
    }
    // ---- fused epilogue ----
    int b = bm >> 4;                 // batch (block-uniform)
    int tt0 = (bm & 15) * 128 + wm;  // sequence pos base (+ mi*16 + lg*4 + j)
    const float qsc = 0.08838834764831845f; // 1/sqrt(128)
    if (bn < 20) {
        bool isQ = (bn < 16);
        short* Ob = isQ ? (Q + (size_t)(b * NH_ + bn) * T_ * HS_)
                        : (Kb + (size_t)(b * NKVH_ + (bn - 16)) * T_ * HS_);
        float sc = isQ ? qsc : 1.0f;
#pragma unroll
        for (int ni = 0; ni < 4; ni++) {
            int d = wn + ni * 16 + lr;           // 0..127 within head
            int i = d >> 1;
            float ssign = (d & 1) ? 1.0f : -1.0f;
            float bv = bias[bn * 128 + d];
#pragma unroll
            for (int mi = 0; mi < 4; mi++) {
                int ttb = tt0 + mi * 16 + lg * 4;
#pragma unroll
                for (int j = 0; j < 4; j++) {
                    float v = acc[mi][ni][j] + bv;
                    float prt = __shfl_xor(v, 1);
                    int tt = ttb + j;
                    float c = fcos[tt * 64 + i], s = fsin[tt * 64 + i];
                    float outv = (v * c + ssign * prt * s) * sc;
                    Ob[(size_t)tt * HS_ + d] = f2bf(outv);
                }
            }
        }
    } else {
        int g = bn - 20;
        short* Vb = VT + (size_t)(b * NKVH_ + g) * HS_ * T_;
#pragma unroll
        for (int ni = 0; ni < 4; ni++) {
            int d = wn + ni * 16 + lr;
            float bv = bias[bn * 128 + d];
#pragma unroll
            for (int mi = 0; mi < 4; mi++) {
                int ttb = tt0 + mi * 16 + lg * 4;
                short pk4[4];
#pragma unroll
                for (int j = 0; j < 4; j++) pk4[j] = f2bf(acc[mi][ni][j] + bv);
                *(int2*)(Vb + (size_t)d * T_ + ttb) = *(const int2*)pk4;
            }
        }
    }
}

// ---------------- Flash attention, causal GQA — swapped-QK^T 32x32, in-register P ----------------
// grid: (B*NH=32 fast, 16 y), qt = (y<8)?y:23-y (CU-complementary pairing). block: 256.
// P path is now FULLY in-register (T12 analog): the packed u32 words previously ds_written
// (w01[sb][k] = P s-pair {8k+4hi, +1}, w23 = {+2,+3} within sb*32) are exchanged across wave
// halves via __shfl_xor(32) with a send/receive mux (each lane SENDS the word its partner
// needs: snd = hi ? w[k0] : w[k1]); all array indices compile-time (rule #20). Removes
// 8 ds_write + 8 ds_read per tile-wave and the 5.9M bank conflicts; LDS 80KB -> 64KB.
// Fragment map (derived from the proven LDS path): pair at s-start p: writer hi'=(p>>2)&1,
// k=(p>>3)&3, word=(p&2)?w23:w01; fragment sc needs p = sc*16+8hi+{0,2,4,6} -> k0=(2sc)&3
// (hi=0) / k1=k0+1 (hi=1); u={own,own,recv,recv} for hi=0, {recv,recv,own,own} for hi=1.
// launch_bounds(256,2): (256,4) spills (round 2). grid.x MUST be 32 (b=bh>>4, round 3).
__global__ __launch_bounds__(256, 2) void attn_kernel(
    const short* __restrict__ Qg, const short* __restrict__ Kg,
    const short* __restrict__ VTg, short* __restrict__ Y)
{
    __shared__ short Ks[2][64 * 128];   // [buf][s][d], swizzled (256B rows, XOR (row&7)<<4)
    __shared__ short VTs[2][128 * 64];  // [buf][d][s], swizzled (128B rows, XOR (row&7)<<4)
    int tid = threadIdx.x, w = tid >> 6, l = tid & 63;
    int l31 = l & 31, hi = l >> 5;
    int yy = blockIdx.y;
    int qt = (yy < 8) ? yy : 23 - yy;   // CU-complementary pairing
    int bh = blockIdx.x;
    int b = bh >> 4, h = bh & 15, g = h >> 2;
    const short* Qb = Qg + (size_t)(b * NH_ + h) * T_ * HS_;
    const short* Kb = Kg + (size_t)(b * NKVH_ + g) * T_ * HS_;
    const short* Vb = VTg + (size_t)(b * NKVH_ + g) * HS_ * T_;

    auto STAGE = [&](int st, int buf) {
#pragma unroll
        for (int i = 0; i < 4; i++) {
            int chunk = w * 4 + i;
            int poff = chunk * 1024 + l * 16;
            int qoffk = poff ^ (((poff >> 8) & 7) << 4);
            async16(Kb + (size_t)(st * 64 + (qoffk >> 8)) * HS_ + ((qoffk & 255) >> 1),
                    (char*)&Ks[buf][0] + chunk * 1024);
            int qoffv = poff ^ (((poff >> 7) & 7) << 4);
            async16(Vb + (size_t)(qoffv >> 7) * T_ + st * 64 + ((qoffv & 127) >> 1),
                    (char*)&VTs[buf][0] + chunk * 1024);
        }
    };

    int qw = qt * 128 + w * 32;      // wave's first q-row
    int qglob = qw + l31;            // this lane's q-row

    s16x8 qf[8];
#pragma unroll
    for (int dc = 0; dc < 8; dc++)
        qf[dc] = *(const s16x8*)(Qb + (size_t)qglob * HS_ + dc * 16 + hi * 8);

    f32x16 oacc[4];
#pragma unroll
    for (int db = 0; db < 4; db++)
#pragma unroll
        for (int i = 0; i < 16; i++) oacc[db][i] = 0.f;
    float m = -1e30f, lsum = 0.f;
    int nst = 2 * qt + 2;

    STAGE(0, 0);
    __syncthreads();
    int cur = 0;

    for (int st = 0; st < nst; ++st) {
        if (st + 1 < nst) STAGE(st + 1, cur ^ 1);   // K+V prefetch flies under compute
        if (st * 64 <= qw) {                        // skip fully-masked tiles (wave-uniform)
            const char* KsC = (const char*)&Ks[cur][0];
            const char* VsC = (const char*)&VTs[cur][0];

            f32x16 sacc[2];
            __builtin_amdgcn_s_setprio(1);
#pragma unroll
            for (int sb = 0; sb < 2; sb++) {
                f32x16 a0, a1;
#pragma unroll
                for (int i = 0; i < 16; i++) { a0[i] = 0.f; a1[i] = 0.f; }
#pragma unroll
                for (int dc = 0; dc < 4; dc++) {
                    int lo0 = (sb * 32 + l31) * 256 + dc * 32 + hi * 16;
                    int po0 = lo0 ^ (((lo0 >> 8) & 7) << 4);
                    s16x8 kf0 = *(const s16x8*)(KsC + po0);
                    a0 = __builtin_amdgcn_mfma_f32_32x32x16_bf16(kf0, qf[dc], a0, 0, 0, 0);
                    int lo1 = (sb * 32 + l31) * 256 + (dc + 4) * 32 + hi * 16;
                    int po1 = lo1 ^ (((lo1 >> 8) & 7) << 4);
                    s16x8 kf1 = *(const s16x8*)(KsC + po1);
                    a1 = __builtin_amdgcn_mfma_f32_32x32x16_bf16(kf1, qf[dc + 4], a1, 0, 0, 0);
                }
#pragma unroll
                for (int i = 0; i < 16; i++) a0[i] += a1[i];
                sacc[sb] = a0;
            }
            __builtin_amdgcn_s_setprio(0);
            if (st * 64 + 63 > qw) {
#pragma unroll
                for (int sb = 0; sb < 2; sb++)
#pragma unroll
                    for (int r = 0; r < 16; r++) {
                        int s = st * 64 + sb * 32 + (r & 3) + 8 * (r >> 2) + 4 * hi;
                        if (s > qglob) sacc[sb][r] = -1e30f;
                    }
            }
            float tm = -1e30f;
#pragma unroll
            for (int sb = 0; sb < 2; sb++)
#pragma unroll
                for (int r = 0; r < 16; r++) tm = fmaxf(tm, sacc[sb][r]);
            tm = fmaxf(tm, __shfl_xor(tm, 32));
            if (__any(tm > m)) {
                float mn = fmaxf(m, tm);
                float corr = __expf(m - mn);
                m = mn; lsum *= corr;
#pragma unroll
                for (int db = 0; db < 4; db++)
#pragma unroll
                    for (int r = 0; r < 16; r++) oacc[db][r] *= corr;
            }
            // P = exp(S^T - m), packed in-register (same words the LDS path wrote)
            unsigned w01[2][4], w23[2][4];
#pragma unroll
            for (int sb = 0; sb < 2; sb++)
#pragma unroll
                for (int k = 0; k < 4; k++) {
                    float p0 = __expf(sacc[sb][4 * k]     - m);
                    float p1 = __expf(sacc[sb][4 * k + 1] - m);
                    float p2 = __expf(sacc[sb][4 * k + 2] - m);
                    float p3 = __expf(sacc[sb][4 * k + 3] - m);
                    lsum += (p0 + p1) + (p2 + p3);
                    w01[sb][k] = (unsigned)(unsigned short)f2bf(p0) | ((unsigned)(unsigned short)f2bf(p1) << 16);
                    w23[sb][k] = (unsigned)(unsigned short)f2bf(p2) | ((unsigned)(unsigned short)f2bf(p3) << 16);
                }
            // O^T += V^T · P ; PV B-operand assembled via cross-half shfl (no LDS)
            __builtin_amdgcn_s_setprio(1);
#pragma unroll
            for (int sc = 0; sc < 4; sc++) {
                const int sb = sc >> 1;
                const int k0 = (2 * sc) & 3, k1 = k0 + 1;
                unsigned ownA = hi ? w01[sb][k1] : w01[sb][k0];
                unsigned ownB = hi ? w23[sb][k1] : w23[sb][k0];
                unsigned sndA = hi ? w01[sb][k0] : w01[sb][k1];   // word the partner needs
                unsigned sndB = hi ? w23[sb][k0] : w23[sb][k1];
                unsigned rcvA = (unsigned)__shfl_xor((int)sndA, 32);
                unsigned rcvB = (unsigned)__shfl_xor((int)sndB, 32);
                unsigned uu[4];
                uu[0] = hi ? rcvA : ownA;
                uu[1] = hi ? rcvB : ownB;
                uu[2] = hi ? ownA : rcvA;
                uu[3] = hi ? ownB : rcvB;
                s16x8 pf = *(const s16x8*)uu;
#pragma unroll
                for (int db = 0; db < 4; db++) {
                    int lo = (db * 32 + l31) * 128 + sc * 32 + hi * 16;
                    int po = lo ^ (((lo >> 7) & 7) << 4);
                    s16x8 vf = *(const s16x8*)(VsC + po);
                    oacc[db] = __builtin_amdgcn_mfma_f32_32x32x16_bf16(vf, pf, oacc[db], 0, 0, 0);
                }
            }
            __builtin_amdgcn_s_setprio(0);
        }
        __syncthreads();
        cur ^= 1;
    }

    lsum += __shfl_xor(lsum, 32);
    float inv = 1.0f / lsum;
    short* Yrow = Y + (size_t)(b * T_ + qglob) * C_ + h * 128;
#pragma unroll
    for (int db = 0; db < 4; db++)
#pragma unroll
        for (int pr = 0; pr < 8; pr++) {
            unsigned u0 = (unsigned short)f2bf(oacc[db][2 * pr] * inv);
            unsigned u1 = (unsigned short)f2bf(oacc[db][2 * pr + 1] * inv);
            int d = db * 32 + ((2 * pr) & 3) + 8 * (pr >> 1) + 4 * hi;
            *(unsigned*)(Yrow + d) = u0 | (u1 << 16);
        }
}

extern "C" void kernel_launch(void* const* d_in, const int* in_sizes, int n_in,
                              void* d_out, int out_size, void* d_ws, size_t ws_size,
                              hipStream_t stream)
{
    const float* x      = (const float*)d_in[0];
    const float* fcos   = (const float*)d_in[1];
    const float* fsin   = (const float*)d_in[2];
    const float* W_attn = (const float*)d_in[3];
    const float* b_attn = (const float*)d_in[4];
    const float* W_proj = (const float*)d_in[5];
    const float* b_proj = (const float*)d_in[6];
    float* out = (float*)d_out;
    char* ws = (char*)d_ws;

    // workspace layout (79.7 MB, no aliasing)
    short* xb  = (short*)(ws + 0);          // 16,777,216
    short* y   = (short*)(ws + 16777216);   // 16,777,216
    short* WpT = (short*)(ws + 33554432);   //  8,388,608
    short* Qb  = (short*)(ws + 41943040);   // 16,777,216
    short* Kb  = (short*)(ws + 58720256);   //  4,194,304
    short* VT  = (short*)(ws + 62914560);   //  4,194,304
    short* WaT = (short*)(ws + 67108864);   // 12,582,912

    prep_kernel<<<4608, 256, 0, stream>>>(x, xb, W_attn, WaT, W_proj, WpT);
    gemm_qkv<<<dim3(32, 24), 256, 0, stream>>>(xb, WaT, b_attn, fcos, fsin, Qb, Kb, VT);
    attn_kernel<<<dim3(32, 16), 256, 0, stream>>>(Qb, Kb, VT, y);
    gemm_bt<<<dim3(32, 16), 256, 0, stream>>>(y, WpT, b_proj, out, NTOK_, C_, C_);
}